// Round 5
// baseline (777.473 us; speedup 1.0000x reference)
//
#include <hip/hip_runtime.h>
#include <stdint.h>

typedef unsigned short u16;
typedef unsigned int u32;
typedef unsigned long long u64;

typedef __attribute__((ext_vector_type(8))) short bfrag;   // 8 bf16 (4 VGPRs)
typedef __attribute__((ext_vector_type(4))) float f32x4;   // 4 fp32 acc

// ---------- bf16 helpers (OCP bf16 = raw upper 16 bits of fp32) ----------
__device__ __forceinline__ float bf2f(u16 u) { return __uint_as_float(((u32)u) << 16); }
__device__ __forceinline__ u16 f2bf(float f) {
    u32 i = __float_as_uint(f);
    u32 r = i + 0x7fffu + ((i >> 16) & 1u);   // round-to-nearest-even
    return (u16)(r >> 16);
}
__device__ __forceinline__ float lo16(u32 u) { return __uint_as_float(u << 16); }
__device__ __forceinline__ float hi16(u32 u) { return __uint_as_float(u & 0xffff0000u); }
__device__ __forceinline__ u32 pack2(float a, float b) {
    return (u32)f2bf(a) | ((u32)f2bf(b) << 16);
}
#define RFL(x) __builtin_amdgcn_readfirstlane(x)

// ---------- CSR build ----------
__global__ void deg_hist(const int* __restrict__ dst, int E, int* __restrict__ deg) {
    int e = blockIdx.x * blockDim.x + threadIdx.x;
    if (e < E) atomicAdd(&deg[dst[e]], 1);
}

#define SCAN_T 256
#define SCAN_E 8
#define SCAN_CHUNK 2048

__global__ void scan_partial(const int* __restrict__ deg, int n, int* __restrict__ partials) {
    __shared__ int sh[SCAN_T];
    int b = blockIdx.x, t = threadIdx.x;
    int base = b * SCAN_CHUNK + t * SCAN_E;
    int s = 0;
#pragma unroll
    for (int i = 0; i < SCAN_E; i++) { int idx = base + i; if (idx < n) s += deg[idx]; }
    sh[t] = s; __syncthreads();
    for (int off = SCAN_T / 2; off > 0; off >>= 1) {
        if (t < off) sh[t] += sh[t + off];
        __syncthreads();
    }
    if (t == 0) partials[b] = sh[0];
}

__global__ void scan_mid(int* __restrict__ partials, int nb) {
    if (threadIdx.x == 0 && blockIdx.x == 0) {
        int acc = 0;
        for (int i = 0; i < nb; i++) { int v = partials[i]; partials[i] = acc; acc += v; }
    }
}

__global__ void scan_final(const int* __restrict__ deg, int n, const int* __restrict__ partials,
                           int* __restrict__ offs, int E) {
    __shared__ int sh[SCAN_T];
    int b = blockIdx.x, t = threadIdx.x;
    int base = b * SCAN_CHUNK + t * SCAN_E;
    int loc[SCAN_E];
    int s = 0;
#pragma unroll
    for (int i = 0; i < SCAN_E; i++) {
        int idx = base + i;
        int v = (idx < n) ? deg[idx] : 0;
        loc[i] = s; s += v;
    }
    sh[t] = s; __syncthreads();
    for (int off = 1; off < SCAN_T; off <<= 1) {
        int v = 0;
        if (t >= off) v = sh[t - off];
        __syncthreads();
        if (t >= off) sh[t] += v;
        __syncthreads();
    }
    int tbase = partials[b] + sh[t] - s;   // exclusive base for this thread
#pragma unroll
    for (int i = 0; i < SCAN_E; i++) { int idx = base + i; if (idx < n) offs[idx] = tbase + loc[i]; }
    if (b == gridDim.x - 1 && t == SCAN_T - 1) offs[n] = E;
}

// cursor = copy of offs; one atomicAdd gives the CSR slot; write (src, orig_edge) as int2
__global__ void csr_fill(const int* __restrict__ srcv, const int* __restrict__ dstv, int E,
                         int* __restrict__ cursor, int2* __restrict__ csr) {
    int e = blockIdx.x * blockDim.x + threadIdx.x;
    if (e < E) {
        int d = dstv[e];
        int p = atomicAdd(&cursor[d], 1);
        csr[p] = make_int2(srcv[e], e);
    }
}

// gather edge_attr (16 fp32 = one 64B cacheline) per CSR slot, write bf16 coalesced
__global__ void csr_copy_ea(const float4* __restrict__ ea, const int2* __restrict__ csr, int E,
                            u64* __restrict__ csr_ea) {
    int p = blockIdx.x * blockDim.x + threadIdx.x;
    if (p < E) {
        int e = csr[p].y;
        const float4* s = ea + (u64)e * 4;
        float4 v0 = s[0], v1 = s[1], v2 = s[2], v3 = s[3];
        u64* d = csr_ea + (u64)p * 4;
        d[0] = (u64)pack2(v0.x, v0.y) | ((u64)pack2(v0.z, v0.w) << 32);
        d[1] = (u64)pack2(v1.x, v1.y) | ((u64)pack2(v1.z, v1.w) << 32);
        d[2] = (u64)pack2(v2.x, v2.y) | ((u64)pack2(v2.z, v2.w) << 32);
        d[3] = (u64)pack2(v3.x, v3.y) | ((u64)pack2(v3.z, v3.w) << 32);
    }
}

// self-loop attr = mean of incoming edge attrs (0 for isolated nodes)
__global__ void loop_mean(const int* __restrict__ offs, const u16* __restrict__ csr_ea, int N,
                          u16* __restrict__ loop_ea) {
    int t = blockIdx.x * blockDim.x + threadIdx.x;
    if (t < N * 16) {
        int n = t >> 4, k = t & 15;
        int a = offs[n], b = offs[n + 1];
        float s = 0.f;
        for (int p = a; p < b; p++) s += bf2f(csr_ea[(u64)p * 16 + k]);
        float m = (b > a) ? s / (float)(b - a) : 0.f;
        loop_ea[t] = f2bf(m);
    }
}

// ---------- W pre-pack: Wl,Wr (fp32, K x 64 each) -> bf16 B-fragment order ----------
// Wb layout: [ct(8)][ks(K/32)][lane(64)][4 dwords]; B-frag: col n=lane&15, k=quad*8+j
template <int K>
__global__ void pack_w(const float* __restrict__ Wl, const float* __restrict__ Wr,
                       u32* __restrict__ Wb) {
    constexpr int NKS = K / 32;
    int t = blockIdx.x * blockDim.x + threadIdx.x;
    if (t >= 8 * NKS * 64) return;
    int lane = t & 63;
    int ks = (t >> 6) % NKS;
    int ct = (t >> 6) / NKS;
    int n = lane & 15, quad = lane >> 4;
    int c = ct * 16 + n;
    const float* W = (c < 64) ? Wl : Wr;
    int cc = c & 63;
    u32* d = Wb + (u64)t * 4;
#pragma unroll
    for (int p = 0; p < 4; p++) {
        int k0 = ks * 32 + quad * 8 + 2 * p;
        d[p] = pack2(W[(u64)k0 * 64 + cc], W[(u64)(k0 + 1) * 64 + cc]);
    }
}

// ---------- MFMA dual GEMM: [xl|xr] = X @ [Wl|Wr] + [bl|br] (bf16 out) ----------
template <int K, bool XF32>
__global__ __launch_bounds__(256) void gemm_mfma(const void* __restrict__ Xv,
                                                 const u32* __restrict__ Wb,
                                                 const float* __restrict__ bl,
                                                 const float* __restrict__ br,
                                                 int N, u16* __restrict__ xl, u16* __restrict__ xr) {
    constexpr int NKS = K / 32;
    int lane = threadIdx.x & 63;
    int gw = (blockIdx.x * 256 + threadIdx.x) >> 6;
    int row0 = gw * 16;
    if (row0 >= N) return;
    int m = lane & 15, quad = lane >> 4;

    f32x4 acc[8];
#pragma unroll
    for (int ct = 0; ct < 8; ct++) acc[ct] = (f32x4){0.f, 0.f, 0.f, 0.f};

#pragma unroll
    for (int ks = 0; ks < NKS; ks++) {
        bfrag a;
        if (XF32) {
            const float* xp = (const float*)Xv + (u64)(row0 + m) * K + ks * 32 + quad * 8;
            float4 v0 = *(const float4*)xp;
            float4 v1 = *(const float4*)(xp + 4);
            union { bfrag v; u32 d[4]; } au;
            au.d[0] = pack2(v0.x, v0.y); au.d[1] = pack2(v0.z, v0.w);
            au.d[2] = pack2(v1.x, v1.y); au.d[3] = pack2(v1.z, v1.w);
            a = au.v;
        } else {
            a = *(const bfrag*)((const u16*)Xv + (u64)(row0 + m) * K + ks * 32 + quad * 8);
        }
#pragma unroll
        for (int ct = 0; ct < 8; ct++) {
            bfrag b = *(const bfrag*)(Wb + (u64)((ct * NKS + ks) * 64 + lane) * 4);
            acc[ct] = __builtin_amdgcn_mfma_f32_16x16x32_bf16(a, b, acc[ct], 0, 0, 0);
        }
    }

    // Epilogue: C/D layout col=lane&15(=m), row=quad*4+reg
#pragma unroll
    for (int ct = 0; ct < 8; ct++) {
        float bv = (ct < 4) ? bl[ct * 16 + m] : br[(ct - 4) * 16 + m];
        u16* dbuf = (ct < 4) ? xl : xr;
        int cc = (ct & 3) * 16 + m;
#pragma unroll
        for (int r = 0; r < 4; r++) {
            int row = row0 + quad * 4 + r;
            dbuf[(u64)row * 64 + cc] = f2bf(acc[ct][r] + bv);
        }
    }
}

// ---------- GATv2 layer: wave/node, batch-4 edges (interleaved latency chains) ----------
__global__ __launch_bounds__(256) void gat_layer(const u16* __restrict__ xl, const u16* __restrict__ xr,
                                                 const int* __restrict__ offs, const int2* __restrict__ csr,
                                                 const u16* __restrict__ csr_ea, const u16* __restrict__ loop_ea,
                                                 const float* __restrict__ We,   // 16 x 64, fp32
                                                 const float* __restrict__ att,  // 64 (= 4x16), fp32
                                                 const float* __restrict__ bias, // 64, fp32
                                                 int N, u16* __restrict__ out) {
    int l = threadIdx.x & 63;            // channel = h*16 + c
    int wid = RFL((int)((blockIdx.x * 256 + threadIdx.x) >> 6));
    int nw = gridDim.x * 4;
    float wec[16];
#pragma unroll
    for (int k = 0; k < 16; k++) wec[k] = We[k * 64 + l];   // We column for this lane
    float att_l = att[l];
    float bias_l = bias[l];
    const u32* ce = (const u32*)csr_ea;       // 8 dwords (16 bf16) per edge
    const u32* le = (const u32*)loop_ea;      // 8 dwords per node

    for (int n = wid; n < N; n += nw) {
        float xr_l = bf2f(xr[(u32)(n * 64 + l)]);
        int a = RFL(offs[n]);
        int b = RFL(offs[n + 1]);
        float lsum, o;

        { // self-loop (src = n, mean attrs)
            float xlv = bf2f(xl[(u32)(n * 64 + l)]);
            const u32* eap = le + (u64)n * 8;
            float z = xr_l;
#pragma unroll
            for (int k = 0; k < 8; k++) {
                u32 u = eap[k];
                z = fmaf(lo16(u), wec[2 * k], z);
                z = fmaf(hi16(u), wec[2 * k + 1], z);
            }
            z += xlv;
            z = fmaxf(z, 0.2f * z);
            float p = z * att_l;
#pragma unroll
            for (int off = 8; off > 0; off >>= 1) p += __shfl_xor(p, off, 64);
            float w = __expf(p);
            lsum = w; o = w * xlv;
        }

        int i = a;
        for (; i + 4 <= b; i += 4) {
            int s0 = RFL(csr[i].x);
            int s1 = RFL(csr[i + 1].x);
            int s2 = RFL(csr[i + 2].x);
            int s3 = RFL(csr[i + 3].x);
            // issue all 4 gathers first (latency overlap with the FMA block)
            float xlv0 = bf2f(xl[(u32)(s0 * 64 + l)]);
            float xlv1 = bf2f(xl[(u32)(s1 * 64 + l)]);
            float xlv2 = bf2f(xl[(u32)(s2 * 64 + l)]);
            float xlv3 = bf2f(xl[(u32)(s3 * 64 + l)]);
            const u32* eap = ce + (u64)i * 8;   // 4 edges = 128B contiguous, wave-uniform
            float z0 = xr_l, z1 = xr_l, z2 = xr_l, z3 = xr_l;
#pragma unroll
            for (int k = 0; k < 8; k++) {
                u32 u0 = eap[k], u1 = eap[8 + k], u2 = eap[16 + k], u3 = eap[24 + k];
                float w0 = wec[2 * k], w1 = wec[2 * k + 1];
                z0 = fmaf(lo16(u0), w0, z0); z0 = fmaf(hi16(u0), w1, z0);
                z1 = fmaf(lo16(u1), w0, z1); z1 = fmaf(hi16(u1), w1, z1);
                z2 = fmaf(lo16(u2), w0, z2); z2 = fmaf(hi16(u2), w1, z2);
                z3 = fmaf(lo16(u3), w0, z3); z3 = fmaf(hi16(u3), w1, z3);
            }
            z0 += xlv0; z1 += xlv1; z2 += xlv2; z3 += xlv3;
            z0 = fmaxf(z0, 0.2f * z0); z1 = fmaxf(z1, 0.2f * z1);
            z2 = fmaxf(z2, 0.2f * z2); z3 = fmaxf(z3, 0.2f * z3);
            float p0 = z0 * att_l, p1 = z1 * att_l, p2 = z2 * att_l, p3 = z3 * att_l;
#pragma unroll
            for (int off = 8; off > 0; off >>= 1) {   // 4 independent trees -> ILP
                p0 += __shfl_xor(p0, off, 64);
                p1 += __shfl_xor(p1, off, 64);
                p2 += __shfl_xor(p2, off, 64);
                p3 += __shfl_xor(p3, off, 64);
            }
            float w0 = __expf(p0), w1 = __expf(p1), w2 = __expf(p2), w3 = __expf(p3);
            lsum += (w0 + w1) + (w2 + w3);
            o = fmaf(w0, xlv0, o);
            o = fmaf(w1, xlv1, o);
            o = fmaf(w2, xlv2, o);
            o = fmaf(w3, xlv3, o);
        }
        for (; i < b; i++) {
            int s0 = RFL(csr[i].x);
            float xlv = bf2f(xl[(u32)(s0 * 64 + l)]);
            const u32* eap = ce + (u64)i * 8;
            float z = xr_l;
#pragma unroll
            for (int k = 0; k < 8; k++) {
                u32 u = eap[k];
                z = fmaf(lo16(u), wec[2 * k], z);
                z = fmaf(hi16(u), wec[2 * k + 1], z);
            }
            z += xlv;
            z = fmaxf(z, 0.2f * z);
            float p = z * att_l;
#pragma unroll
            for (int off = 8; off > 0; off >>= 1) p += __shfl_xor(p, off, 64);
            float w = __expf(p);
            lsum += w;
            o = fmaf(w, xlv, o);
        }

        float res = o / (lsum + 1e-16f) + bias_l;
        res = fmaxf(res, 0.f);                        // relu after each GAT layer
        out[(u32)(n * 64 + l)] = f2bf(res);
    }
}

// ---------- MLP head: relu(h @ W1 + b1) @ W2 + b2 -> sigmoid (fp32 out) ----------
__global__ __launch_bounds__(256) void mlp_head(const u16* __restrict__ h,
                                                const float* __restrict__ W1, const float* __restrict__ b1,
                                                const float* __restrict__ W2, const float* __restrict__ b2,
                                                int N, float* __restrict__ out) {
    __shared__ float w1[64 * 16];
    __shared__ float sb1[16];
    __shared__ float w2[16];
    for (int i = threadIdx.x; i < 64 * 16; i += 256) w1[i] = W1[i];
    if (threadIdx.x < 16) { sb1[threadIdx.x] = b1[threadIdx.x]; w2[threadIdx.x] = W2[threadIdx.x]; }
    __syncthreads();
    float b2v = b2[0];
    int n = blockIdx.x * blockDim.x + threadIdx.x;
    if (n < N) {
        float hv[64];
        const u32* hp = (const u32*)(h + (u64)n * 64);
#pragma unroll
        for (int i = 0; i < 32; i++) { u32 u = hp[i]; hv[2 * i] = lo16(u); hv[2 * i + 1] = hi16(u); }
        float z = b2v;
        for (int j = 0; j < 16; j++) {
            float acc = sb1[j];
#pragma unroll
            for (int k = 0; k < 64; k++) acc = fmaf(hv[k], w1[k * 16 + j], acc);
            acc = fmaxf(acc, 0.f);
            z = fmaf(acc, w2[j], z);
        }
        out[n] = 1.f / (1.f + __expf(-z));
    }
}

// ---------- launch ----------
extern "C" void kernel_launch(void* const* d_in, const int* in_sizes, int n_in,
                              void* d_out, int out_size, void* d_ws, size_t ws_size,
                              hipStream_t stream) {
    const float* x    = (const float*)d_in[0];
    const int*   ei   = (const int*)d_in[1];
    const float* ea   = (const float*)d_in[2];
    const float* Wl1  = (const float*)d_in[3];
    const float* bl1  = (const float*)d_in[4];
    const float* Wr1  = (const float*)d_in[5];
    const float* br1  = (const float*)d_in[6];
    const float* We1  = (const float*)d_in[7];
    const float* att1 = (const float*)d_in[8];
    const float* bias1= (const float*)d_in[9];
    const float* Wl2  = (const float*)d_in[10];
    const float* bl2  = (const float*)d_in[11];
    const float* Wr2  = (const float*)d_in[12];
    const float* br2  = (const float*)d_in[13];
    const float* We2  = (const float*)d_in[14];
    const float* att2 = (const float*)d_in[15];
    const float* bias2= (const float*)d_in[16];
    const float* W1   = (const float*)d_in[17];
    const float* b1   = (const float*)d_in[18];
    const float* W2   = (const float*)d_in[19];
    const float* b2   = (const float*)d_in[20];
    float* out = (float*)d_out;

    const int N = in_sizes[0] / 128;
    const int E = in_sizes[1] / 2;
    const int* srcv = ei;
    const int* dstv = ei + E;

    uint8_t* p = (uint8_t*)d_ws;
    auto carve = [&](size_t bytes) -> void* {
        void* r = (void*)p;
        p += (bytes + 255) & ~(size_t)255;
        return r;
    };
    int* deg     = (int*)carve((size_t)N * 4);
    int* cursor  = (int*)carve((size_t)N * 4);
    int* offs    = (int*)carve((size_t)(N + 1) * 4);
    int* partials= (int*)carve(4096);
    int2* csr    = (int2*)carve((size_t)E * 8);
    u16* csr_ea  = (u16*)carve((size_t)E * 16 * 2);
    u16* loop_ea = (u16*)carve((size_t)N * 16 * 2);
    u16* xl      = (u16*)carve((size_t)N * 64 * 2);
    u16* xr      = (u16*)carve((size_t)N * 64 * 2);
    u16* hb      = (u16*)carve((size_t)N * 64 * 2);
    u32* wb1     = (u32*)carve(8 * 4 * 64 * 16);   // K=128 packed W
    u32* wb2     = (u32*)carve(8 * 2 * 64 * 16);   // K=64 packed W
    (void)ws_size; (void)n_in; (void)out_size;

    hipMemsetAsync(deg, 0, (size_t)N * 4, stream);

    const int B = 256;
    // W pre-pack (tiny)
    pack_w<128><<<8, 256, 0, stream>>>(Wl1, Wr1, wb1);
    pack_w<64><<<4, 256, 0, stream>>>(Wl2, Wr2, wb2);

    deg_hist<<<(E + B - 1) / B, B, 0, stream>>>(dstv, E, deg);
    int nb = (N + SCAN_CHUNK - 1) / SCAN_CHUNK;
    scan_partial<<<nb, SCAN_T, 0, stream>>>(deg, N, partials);
    scan_mid<<<1, 64, 0, stream>>>(partials, nb);
    scan_final<<<nb, SCAN_T, 0, stream>>>(deg, N, partials, offs, E);
    hipMemcpyAsync(cursor, offs, (size_t)N * 4, hipMemcpyDeviceToDevice, stream);
    csr_fill<<<(E + B - 1) / B, B, 0, stream>>>(srcv, dstv, E, cursor, csr);
    csr_copy_ea<<<(E + B - 1) / B, B, 0, stream>>>((const float4*)ea, csr, E, (u64*)csr_ea);
    loop_mean<<<(16 * N + B - 1) / B, B, 0, stream>>>(offs, csr_ea, N, loop_ea);

    int gemm_blocks = (N / 16 + 3) / 4;   // one wave per 16 rows, 4 waves/block
    // Layer 1
    gemm_mfma<128, true><<<gemm_blocks, 256, 0, stream>>>(x, wb1, bl1, br1, N, xl, xr);
    gat_layer<<<8192, 256, 0, stream>>>(xl, xr, offs, csr, csr_ea, loop_ea, We1, att1, bias1, N, hb);
    // Layer 2
    gemm_mfma<64, false><<<gemm_blocks, 256, 0, stream>>>(hb, wb2, bl2, br2, N, xl, xr);
    gat_layer<<<8192, 256, 0, stream>>>(xl, xr, offs, csr, csr_ea, loop_ea, We2, att2, bias2, N, hb);
    // Head
    mlp_head<<<(N + B - 1) / B, B, 0, stream>>>(hb, W1, b1, W2, b2, N, out);
}

// Round 6
// 724.683 us; speedup vs baseline: 1.0728x; 1.0728x over previous
//
#include <hip/hip_runtime.h>
#include <stdint.h>

typedef unsigned short u16;
typedef unsigned int u32;
typedef unsigned long long u64;

typedef __attribute__((ext_vector_type(8))) short bfrag;   // 8 bf16 (4 VGPRs)
typedef __attribute__((ext_vector_type(4))) float f32x4;   // 4 fp32 acc

// ---------- bf16 helpers (OCP bf16 = raw upper 16 bits of fp32) ----------
__device__ __forceinline__ float bf2f(u16 u) { return __uint_as_float(((u32)u) << 16); }
__device__ __forceinline__ u16 f2bf(float f) {
    u32 i = __float_as_uint(f);
    u32 r = i + 0x7fffu + ((i >> 16) & 1u);   // round-to-nearest-even
    return (u16)(r >> 16);
}
__device__ __forceinline__ float lo16(u32 u) { return __uint_as_float(u << 16); }
__device__ __forceinline__ float hi16(u32 u) { return __uint_as_float(u & 0xffff0000u); }
__device__ __forceinline__ u32 pack2(float a, float b) {
    return (u32)f2bf(a) | ((u32)f2bf(b) << 16);
}
#define RFL(x) __builtin_amdgcn_readfirstlane(x)

// 16-lane (row) sum via DPP row_ror rotate-adds: 4 dependent v_add_f32, no LDS pipe.
// dpp_ctrl: row_ror:N = 0x120|N
#define DPP_ROR_ADD(p, ctrl) \
    p += __int_as_float(__builtin_amdgcn_update_dpp(0, __float_as_int(p), ctrl, 0xF, 0xF, false))
__device__ __forceinline__ float red16(float p) {
    DPP_ROR_ADD(p, 0x128);   // ror 8
    DPP_ROR_ADD(p, 0x124);   // ror 4
    DPP_ROR_ADD(p, 0x122);   // ror 2
    DPP_ROR_ADD(p, 0x121);   // ror 1
    return p;                // every lane in the 16-row holds the row sum
}

// ---------- CSR build ----------
__global__ void deg_hist(const int* __restrict__ dst, int E, int* __restrict__ deg) {
    int e = blockIdx.x * blockDim.x + threadIdx.x;
    if (e < E) atomicAdd(&deg[dst[e]], 1);
}

#define SCAN_T 256
#define SCAN_E 8
#define SCAN_CHUNK 2048

__global__ void scan_partial(const int* __restrict__ deg, int n, int* __restrict__ partials) {
    __shared__ int sh[SCAN_T];
    int b = blockIdx.x, t = threadIdx.x;
    int base = b * SCAN_CHUNK + t * SCAN_E;
    int s = 0;
#pragma unroll
    for (int i = 0; i < SCAN_E; i++) { int idx = base + i; if (idx < n) s += deg[idx]; }
    sh[t] = s; __syncthreads();
    for (int off = SCAN_T / 2; off > 0; off >>= 1) {
        if (t < off) sh[t] += sh[t + off];
        __syncthreads();
    }
    if (t == 0) partials[b] = sh[0];
}

__global__ void scan_mid(int* __restrict__ partials, int nb) {
    if (threadIdx.x == 0 && blockIdx.x == 0) {
        int acc = 0;
        for (int i = 0; i < nb; i++) { int v = partials[i]; partials[i] = acc; acc += v; }
    }
}

__global__ void scan_final(const int* __restrict__ deg, int n, const int* __restrict__ partials,
                           int* __restrict__ offs, int E) {
    __shared__ int sh[SCAN_T];
    int b = blockIdx.x, t = threadIdx.x;
    int base = b * SCAN_CHUNK + t * SCAN_E;
    int loc[SCAN_E];
    int s = 0;
#pragma unroll
    for (int i = 0; i < SCAN_E; i++) {
        int idx = base + i;
        int v = (idx < n) ? deg[idx] : 0;
        loc[i] = s; s += v;
    }
    sh[t] = s; __syncthreads();
    for (int off = 1; off < SCAN_T; off <<= 1) {
        int v = 0;
        if (t >= off) v = sh[t - off];
        __syncthreads();
        if (t >= off) sh[t] += v;
        __syncthreads();
    }
    int tbase = partials[b] + sh[t] - s;   // exclusive base for this thread
#pragma unroll
    for (int i = 0; i < SCAN_E; i++) { int idx = base + i; if (idx < n) offs[idx] = tbase + loc[i]; }
    if (b == gridDim.x - 1 && t == SCAN_T - 1) offs[n] = E;
}

// cursor = copy of offs; one atomicAdd gives the CSR slot; write (src, orig_edge) as int2
__global__ void csr_fill(const int* __restrict__ srcv, const int* __restrict__ dstv, int E,
                         int* __restrict__ cursor, int2* __restrict__ csr) {
    int e = blockIdx.x * blockDim.x + threadIdx.x;
    if (e < E) {
        int d = dstv[e];
        int p = atomicAdd(&cursor[d], 1);
        csr[p] = make_int2(srcv[e], e);
    }
}

// gather edge_attr (16 fp32 = one 64B cacheline) per CSR slot, write bf16 coalesced
__global__ void csr_copy_ea(const float4* __restrict__ ea, const int2* __restrict__ csr, int E,
                            u64* __restrict__ csr_ea) {
    int p = blockIdx.x * blockDim.x + threadIdx.x;
    if (p < E) {
        int e = csr[p].y;
        const float4* s = ea + (u64)e * 4;
        float4 v0 = s[0], v1 = s[1], v2 = s[2], v3 = s[3];
        u64* d = csr_ea + (u64)p * 4;
        d[0] = (u64)pack2(v0.x, v0.y) | ((u64)pack2(v0.z, v0.w) << 32);
        d[1] = (u64)pack2(v1.x, v1.y) | ((u64)pack2(v1.z, v1.w) << 32);
        d[2] = (u64)pack2(v2.x, v2.y) | ((u64)pack2(v2.z, v2.w) << 32);
        d[3] = (u64)pack2(v3.x, v3.y) | ((u64)pack2(v3.z, v3.w) << 32);
    }
}

// self-loop attr = mean of incoming edge attrs (0 for isolated nodes); 4-way ILP
__global__ void loop_mean(const int* __restrict__ offs, const u16* __restrict__ csr_ea, int N,
                          u16* __restrict__ loop_ea) {
    int t = blockIdx.x * blockDim.x + threadIdx.x;
    if (t < N * 16) {
        int n = t >> 4, k = t & 15;
        int a = offs[n], b = offs[n + 1];
        float s0 = 0.f, s1 = 0.f, s2 = 0.f, s3 = 0.f;
        int p = a;
        for (; p + 4 <= b; p += 4) {
            s0 += bf2f(csr_ea[(u64)p * 16 + k]);
            s1 += bf2f(csr_ea[(u64)(p + 1) * 16 + k]);
            s2 += bf2f(csr_ea[(u64)(p + 2) * 16 + k]);
            s3 += bf2f(csr_ea[(u64)(p + 3) * 16 + k]);
        }
        for (; p < b; p++) s0 += bf2f(csr_ea[(u64)p * 16 + k]);
        float s = (s0 + s1) + (s2 + s3);
        float m = (b > a) ? s / (float)(b - a) : 0.f;
        loop_ea[t] = f2bf(m);
    }
}

// ---------- W pre-pack: Wl,Wr (fp32, K x 64 each) -> bf16 B-fragment order ----------
// Wb layout: [ct(8)][ks(K/32)][lane(64)][4 dwords]; B-frag: col n=lane&15, k=quad*8+j
template <int K>
__global__ void pack_w(const float* __restrict__ Wl, const float* __restrict__ Wr,
                       u32* __restrict__ Wb) {
    constexpr int NKS = K / 32;
    int t = blockIdx.x * blockDim.x + threadIdx.x;
    if (t >= 8 * NKS * 64) return;
    int lane = t & 63;
    int ks = (t >> 6) % NKS;
    int ct = (t >> 6) / NKS;
    int n = lane & 15, quad = lane >> 4;
    int c = ct * 16 + n;
    const float* W = (c < 64) ? Wl : Wr;
    int cc = c & 63;
    u32* d = Wb + (u64)t * 4;
#pragma unroll
    for (int p = 0; p < 4; p++) {
        int k0 = ks * 32 + quad * 8 + 2 * p;
        d[p] = pack2(W[(u64)k0 * 64 + cc], W[(u64)(k0 + 1) * 64 + cc]);
    }
}

// ---------- MFMA dual GEMM: [xl|xr] = X @ [Wl|Wr] + [bl|br] (bf16 out) ----------
template <int K, bool XF32>
__global__ __launch_bounds__(256) void gemm_mfma(const void* __restrict__ Xv,
                                                 const u32* __restrict__ Wb,
                                                 const float* __restrict__ bl,
                                                 const float* __restrict__ br,
                                                 int N, u16* __restrict__ xl, u16* __restrict__ xr) {
    constexpr int NKS = K / 32;
    int lane = threadIdx.x & 63;
    int gw = (blockIdx.x * 256 + threadIdx.x) >> 6;
    int row0 = gw * 16;
    if (row0 >= N) return;
    int m = lane & 15, quad = lane >> 4;

    f32x4 acc[8];
#pragma unroll
    for (int ct = 0; ct < 8; ct++) acc[ct] = (f32x4){0.f, 0.f, 0.f, 0.f};

#pragma unroll
    for (int ks = 0; ks < NKS; ks++) {
        bfrag a;
        if (XF32) {
            const float* xp = (const float*)Xv + (u64)(row0 + m) * K + ks * 32 + quad * 8;
            float4 v0 = *(const float4*)xp;
            float4 v1 = *(const float4*)(xp + 4);
            union { bfrag v; u32 d[4]; } au;
            au.d[0] = pack2(v0.x, v0.y); au.d[1] = pack2(v0.z, v0.w);
            au.d[2] = pack2(v1.x, v1.y); au.d[3] = pack2(v1.z, v1.w);
            a = au.v;
        } else {
            a = *(const bfrag*)((const u16*)Xv + (u64)(row0 + m) * K + ks * 32 + quad * 8);
        }
#pragma unroll
        for (int ct = 0; ct < 8; ct++) {
            bfrag b = *(const bfrag*)(Wb + (u64)((ct * NKS + ks) * 64 + lane) * 4);
            acc[ct] = __builtin_amdgcn_mfma_f32_16x16x32_bf16(a, b, acc[ct], 0, 0, 0);
        }
    }

    // Epilogue: C/D layout col=lane&15(=m), row=quad*4+reg
#pragma unroll
    for (int ct = 0; ct < 8; ct++) {
        float bv = (ct < 4) ? bl[ct * 16 + m] : br[(ct - 4) * 16 + m];
        u16* dbuf = (ct < 4) ? xl : xr;
        int cc = (ct & 3) * 16 + m;
#pragma unroll
        for (int r = 0; r < 4; r++) {
            int row = row0 + quad * 4 + r;
            dbuf[(u64)row * 64 + cc] = f2bf(acc[ct][r] + bv);
        }
    }
}

// ---------- GATv2 layer: wave/node, scalar edge attrs, DPP head-reduce ----------
__global__ __launch_bounds__(256) void gat_layer(const u16* __restrict__ xl, const u16* __restrict__ xr,
                                                 const int* __restrict__ offs, const int2* __restrict__ csr,
                                                 const u16* __restrict__ csr_ea, const u16* __restrict__ loop_ea,
                                                 const float* __restrict__ We,   // 16 x 64, fp32
                                                 const float* __restrict__ att,  // 64 (= 4x16), fp32
                                                 const float* __restrict__ bias, // 64, fp32
                                                 int N, u16* __restrict__ out) {
    int l = threadIdx.x & 63;            // channel = h*16 + c
    int wid = RFL((int)((blockIdx.x * 256 + threadIdx.x) >> 6));
    int nw = gridDim.x * 4;
    float wec[16];
#pragma unroll
    for (int k = 0; k < 16; k++) wec[k] = We[k * 64 + l];   // We column for this lane
    float att_l = att[l];
    float bias_l = bias[l];
    const u32* ce = (const u32*)csr_ea;       // 8 dwords (16 bf16) per edge
    const u32* le = (const u32*)loop_ea;      // 8 dwords per node

    for (int n = wid; n < N; n += nw) {
        float xr_l = bf2f(xr[(u32)(n * 64 + l)]);
        int a = RFL(offs[n]);
        int b = RFL(offs[n + 1]);
        float lsum = 0.f, o = 0.f;

        auto edge_u = [&](const u32* eap, int srcn) {
            float xlv = bf2f(xl[(u32)(srcn * 64 + l)]);
            float z = xr_l;
#pragma unroll
            for (int k = 0; k < 8; k++) {
                u32 u = eap[k];                       // wave-uniform -> s_load, scalar unpack
                z = fmaf(lo16(u), wec[2 * k], z);
                z = fmaf(hi16(u), wec[2 * k + 1], z);
            }
            z += xlv;
            z = fmaxf(z, 0.2f * z);                   // leaky_relu(0.2)
            float w = __expf(red16(z * att_l));       // DPP 16-lane sum, then exp
            lsum += w;
            o = fmaf(w, xlv, o);
        };

        edge_u(le + (u64)n * 8, n);                   // self-loop (mean attrs)
        int i = a;
        for (; i < b - 1; i += 2) {                   // 2x unroll (R4 structure: SGPR-lean)
            int s0 = RFL(csr[i].x);
            int s1 = RFL(csr[i + 1].x);
            edge_u(ce + (u64)i * 8, s0);
            edge_u(ce + (u64)(i + 1) * 8, s1);
        }
        if (i < b) edge_u(ce + (u64)i * 8, RFL(csr[i].x));

        float res = o / (lsum + 1e-16f) + bias_l;
        res = fmaxf(res, 0.f);                        // relu after each GAT layer
        out[(u32)(n * 64 + l)] = f2bf(res);
    }
}

// ---------- MLP head: relu(h @ W1 + b1) @ W2 + b2 -> sigmoid (fp32 out) ----------
__global__ __launch_bounds__(256) void mlp_head(const u16* __restrict__ h,
                                                const float* __restrict__ W1, const float* __restrict__ b1,
                                                const float* __restrict__ W2, const float* __restrict__ b2,
                                                int N, float* __restrict__ out) {
    __shared__ float w1[64 * 16];
    __shared__ float sb1[16];
    __shared__ float w2[16];
    for (int i = threadIdx.x; i < 64 * 16; i += 256) w1[i] = W1[i];
    if (threadIdx.x < 16) { sb1[threadIdx.x] = b1[threadIdx.x]; w2[threadIdx.x] = W2[threadIdx.x]; }
    __syncthreads();
    float b2v = b2[0];
    int n = blockIdx.x * blockDim.x + threadIdx.x;
    if (n < N) {
        float hv[64];
        const u32* hp = (const u32*)(h + (u64)n * 64);
#pragma unroll
        for (int i = 0; i < 32; i++) { u32 u = hp[i]; hv[2 * i] = lo16(u); hv[2 * i + 1] = hi16(u); }
        float z = b2v;
        for (int j = 0; j < 16; j++) {
            float acc = sb1[j];
#pragma unroll
            for (int k = 0; k < 64; k++) acc = fmaf(hv[k], w1[k * 16 + j], acc);
            acc = fmaxf(acc, 0.f);
            z = fmaf(acc, w2[j], z);
        }
        out[n] = 1.f / (1.f + __expf(-z));
    }
}

// ---------- launch ----------
extern "C" void kernel_launch(void* const* d_in, const int* in_sizes, int n_in,
                              void* d_out, int out_size, void* d_ws, size_t ws_size,
                              hipStream_t stream) {
    const float* x    = (const float*)d_in[0];
    const int*   ei   = (const int*)d_in[1];
    const float* ea   = (const float*)d_in[2];
    const float* Wl1  = (const float*)d_in[3];
    const float* bl1  = (const float*)d_in[4];
    const float* Wr1  = (const float*)d_in[5];
    const float* br1  = (const float*)d_in[6];
    const float* We1  = (const float*)d_in[7];
    const float* att1 = (const float*)d_in[8];
    const float* bias1= (const float*)d_in[9];
    const float* Wl2  = (const float*)d_in[10];
    const float* bl2  = (const float*)d_in[11];
    const float* Wr2  = (const float*)d_in[12];
    const float* br2  = (const float*)d_in[13];
    const float* We2  = (const float*)d_in[14];
    const float* att2 = (const float*)d_in[15];
    const float* bias2= (const float*)d_in[16];
    const float* W1   = (const float*)d_in[17];
    const float* b1   = (const float*)d_in[18];
    const float* W2   = (const float*)d_in[19];
    const float* b2   = (const float*)d_in[20];
    float* out = (float*)d_out;

    const int N = in_sizes[0] / 128;
    const int E = in_sizes[1] / 2;
    const int* srcv = ei;
    const int* dstv = ei + E;

    uint8_t* p = (uint8_t*)d_ws;
    auto carve = [&](size_t bytes) -> void* {
        void* r = (void*)p;
        p += (bytes + 255) & ~(size_t)255;
        return r;
    };
    int* deg     = (int*)carve((size_t)N * 4);
    int* cursor  = (int*)carve((size_t)N * 4);
    int* offs    = (int*)carve((size_t)(N + 1) * 4);
    int* partials= (int*)carve(4096);
    int2* csr    = (int2*)carve((size_t)E * 8);
    u16* csr_ea  = (u16*)carve((size_t)E * 16 * 2);
    u16* loop_ea = (u16*)carve((size_t)N * 16 * 2);
    u16* xl      = (u16*)carve((size_t)N * 64 * 2);
    u16* xr      = (u16*)carve((size_t)N * 64 * 2);
    u16* hb      = (u16*)carve((size_t)N * 64 * 2);
    u32* wb1     = (u32*)carve(8 * 4 * 64 * 16);   // K=128 packed W
    u32* wb2     = (u32*)carve(8 * 2 * 64 * 16);   // K=64 packed W
    (void)ws_size; (void)n_in; (void)out_size;

    hipMemsetAsync(deg, 0, (size_t)N * 4, stream);

    const int B = 256;
    // W pre-pack (tiny)
    pack_w<128><<<8, 256, 0, stream>>>(Wl1, Wr1, wb1);
    pack_w<64><<<4, 256, 0, stream>>>(Wl2, Wr2, wb2);

    deg_hist<<<(E + B - 1) / B, B, 0, stream>>>(dstv, E, deg);
    int nb = (N + SCAN_CHUNK - 1) / SCAN_CHUNK;
    scan_partial<<<nb, SCAN_T, 0, stream>>>(deg, N, partials);
    scan_mid<<<1, 64, 0, stream>>>(partials, nb);
    scan_final<<<nb, SCAN_T, 0, stream>>>(deg, N, partials, offs, E);
    hipMemcpyAsync(cursor, offs, (size_t)N * 4, hipMemcpyDeviceToDevice, stream);
    csr_fill<<<(E + B - 1) / B, B, 0, stream>>>(srcv, dstv, E, cursor, csr);
    csr_copy_ea<<<(E + B - 1) / B, B, 0, stream>>>((const float4*)ea, csr, E, (u64*)csr_ea);
    loop_mean<<<(16 * N + B - 1) / B, B, 0, stream>>>(offs, csr_ea, N, loop_ea);

    int gemm_blocks = (N / 16 + 3) / 4;   // one wave per 16 rows, 4 waves/block
    // Layer 1
    gemm_mfma<128, true><<<gemm_blocks, 256, 0, stream>>>(x, wb1, bl1, br1, N, xl, xr);
    gat_layer<<<8192, 256, 0, stream>>>(xl, xr, offs, csr, csr_ea, loop_ea, We1, att1, bias1, N, hb);
    // Layer 2
    gemm_mfma<64, false><<<gemm_blocks, 256, 0, stream>>>(hb, wb2, bl2, br2, N, xl, xr);
    gat_layer<<<8192, 256, 0, stream>>>(xl, xr, offs, csr, csr_ea, loop_ea, We2, att2, bias2, N, hb);
    // Head
    mlp_head<<<(N + B - 1) / B, B, 0, stream>>>(hb, W1, b1, W2, b2, N, out);
}

// Round 7
// 648.886 us; speedup vs baseline: 1.1982x; 1.1168x over previous
//
#include <hip/hip_runtime.h>
#include <stdint.h>

typedef unsigned short u16;
typedef unsigned int u32;
typedef unsigned long long u64;

typedef __attribute__((ext_vector_type(8))) short bfrag;   // 8 bf16 (4 VGPRs)
typedef __attribute__((ext_vector_type(4))) float f32x4;   // 4 fp32 acc

// ---------- bf16 helpers (OCP bf16 = raw upper 16 bits of fp32) ----------
__device__ __forceinline__ float bf2f(u16 u) { return __uint_as_float(((u32)u) << 16); }
__device__ __forceinline__ u16 f2bf(float f) {
    u32 i = __float_as_uint(f);
    u32 r = i + 0x7fffu + ((i >> 16) & 1u);   // round-to-nearest-even
    return (u16)(r >> 16);
}
__device__ __forceinline__ float lo16(u32 u) { return __uint_as_float(u << 16); }
__device__ __forceinline__ float hi16(u32 u) { return __uint_as_float(u & 0xffff0000u); }
__device__ __forceinline__ u32 pack2(float a, float b) {
    return (u32)f2bf(a) | ((u32)f2bf(b) << 16);
}
#define RFL(x) __builtin_amdgcn_readfirstlane(x)

// 16-lane (row) sum via DPP row_ror rotate-adds: 4 dependent v_add_f32, no LDS pipe.
#define DPP_ROR_ADD(p, ctrl) \
    p += __int_as_float(__builtin_amdgcn_update_dpp(0, __float_as_int(p), ctrl, 0xF, 0xF, false))
__device__ __forceinline__ float red16(float p) {
    DPP_ROR_ADD(p, 0x128);   // ror 8
    DPP_ROR_ADD(p, 0x124);   // ror 4
    DPP_ROR_ADD(p, 0x122);   // ror 2
    DPP_ROR_ADD(p, 0x121);   // ror 1
    return p;                // every lane in the 16-row holds the row sum
}

// ---------- CSR build ----------
__global__ void deg_hist(const int* __restrict__ dst, int E, int* __restrict__ deg) {
    int e = blockIdx.x * blockDim.x + threadIdx.x;
    if (e < E) atomicAdd(&deg[dst[e]], 1);
}

#define SCAN_T 256
#define SCAN_E 8
#define SCAN_CHUNK 2048

__global__ void scan_partial(const int* __restrict__ deg, int n, int* __restrict__ partials) {
    __shared__ int sh[SCAN_T];
    int b = blockIdx.x, t = threadIdx.x;
    int base = b * SCAN_CHUNK + t * SCAN_E;
    int s = 0;
#pragma unroll
    for (int i = 0; i < SCAN_E; i++) { int idx = base + i; if (idx < n) s += deg[idx]; }
    sh[t] = s; __syncthreads();
    for (int off = SCAN_T / 2; off > 0; off >>= 1) {
        if (t < off) sh[t] += sh[t + off];
        __syncthreads();
    }
    if (t == 0) partials[b] = sh[0];
}

__global__ void scan_mid(int* __restrict__ partials, int nb) {
    if (threadIdx.x == 0 && blockIdx.x == 0) {
        int acc = 0;
        for (int i = 0; i < nb; i++) { int v = partials[i]; partials[i] = acc; acc += v; }
    }
}

__global__ void scan_final(const int* __restrict__ deg, int n, const int* __restrict__ partials,
                           int* __restrict__ offs, int E) {
    __shared__ int sh[SCAN_T];
    int b = blockIdx.x, t = threadIdx.x;
    int base = b * SCAN_CHUNK + t * SCAN_E;
    int loc[SCAN_E];
    int s = 0;
#pragma unroll
    for (int i = 0; i < SCAN_E; i++) {
        int idx = base + i;
        int v = (idx < n) ? deg[idx] : 0;
        loc[i] = s; s += v;
    }
    sh[t] = s; __syncthreads();
    for (int off = 1; off < SCAN_T; off <<= 1) {
        int v = 0;
        if (t >= off) v = sh[t - off];
        __syncthreads();
        if (t >= off) sh[t] += v;
        __syncthreads();
    }
    int tbase = partials[b] + sh[t] - s;   // exclusive base for this thread
#pragma unroll
    for (int i = 0; i < SCAN_E; i++) { int idx = base + i; if (idx < n) offs[idx] = tbase + loc[i]; }
    if (b == gridDim.x - 1 && t == SCAN_T - 1) offs[n] = E;
}

// ---------- fused CSR fill: one 64B (or 40B) record per edge = src + bf16 attrs ----------
// record dwords: [0]=src [1]=pad [2..9]=16 bf16 attrs [10..RS) = pad
template <int RS>
__global__ void csr_fill_ea(const int* __restrict__ srcv, const int* __restrict__ dstv,
                            const float4* __restrict__ ea, int E,
                            int* __restrict__ cursor, u32* __restrict__ rec) {
    int e = blockIdx.x * blockDim.x + threadIdx.x;
    if (e >= E) return;
    const float4* s = ea + (u64)e * 4;
    float4 v0 = s[0], v1 = s[1], v2 = s[2], v3 = s[3];
    u32 a0 = pack2(v0.x, v0.y), a1 = pack2(v0.z, v0.w);
    u32 a2 = pack2(v1.x, v1.y), a3 = pack2(v1.z, v1.w);
    u32 a4 = pack2(v2.x, v2.y), a5 = pack2(v2.z, v2.w);
    u32 a6 = pack2(v3.x, v3.y), a7 = pack2(v3.z, v3.w);
    int sr = srcv[e];
    int d = dstv[e];
    int p = atomicAdd(&cursor[d], 1);
    u32* r = rec + (u64)p * RS;
    if (RS == 16) {              // full-cacheline record: clean 64B line write, no RMW
        uint4* q = (uint4*)r;
        q[0] = make_uint4((u32)sr, 0u, a0, a1);
        q[1] = make_uint4(a2, a3, a4, a5);
        q[2] = make_uint4(a6, a7, 0u, 0u);
        q[3] = make_uint4(0u, 0u, 0u, 0u);
    } else {                     // 40B record (8B-aligned), smaller footprint
        u64* q = (u64*)r;
        q[0] = (u64)(u32)sr;
        q[1] = (u64)a0 | ((u64)a1 << 32);
        q[2] = (u64)a2 | ((u64)a3 << 32);
        q[3] = (u64)a4 | ((u64)a5 << 32);
        q[4] = (u64)a6 | ((u64)a7 << 32);
    }
}

// self-loop attr = mean of incoming edge attrs (0 for isolated nodes); 4-way ILP
template <int RS>
__global__ void loop_mean(const int* __restrict__ offs, const u16* __restrict__ rec16, int N,
                          u16* __restrict__ loop_ea) {
    int t = blockIdx.x * blockDim.x + threadIdx.x;
    if (t < N * 16) {
        int n = t >> 4, k = t & 15;
        int a = offs[n], b = offs[n + 1];
        float s0 = 0.f, s1 = 0.f, s2 = 0.f, s3 = 0.f;
        int p = a;
        for (; p + 4 <= b; p += 4) {
            s0 += bf2f(rec16[(u64)p * (2 * RS) + 4 + k]);
            s1 += bf2f(rec16[(u64)(p + 1) * (2 * RS) + 4 + k]);
            s2 += bf2f(rec16[(u64)(p + 2) * (2 * RS) + 4 + k]);
            s3 += bf2f(rec16[(u64)(p + 3) * (2 * RS) + 4 + k]);
        }
        for (; p < b; p++) s0 += bf2f(rec16[(u64)p * (2 * RS) + 4 + k]);
        float s = (s0 + s1) + (s2 + s3);
        float m = (b > a) ? s / (float)(b - a) : 0.f;
        loop_ea[t] = f2bf(m);
    }
}

// ---------- W pre-pack: Wl,Wr (fp32, K x 64 each) -> bf16 B-fragment order ----------
template <int K>
__global__ void pack_w(const float* __restrict__ Wl, const float* __restrict__ Wr,
                       u32* __restrict__ Wb) {
    constexpr int NKS = K / 32;
    int t = blockIdx.x * blockDim.x + threadIdx.x;
    if (t >= 8 * NKS * 64) return;
    int lane = t & 63;
    int ks = (t >> 6) % NKS;
    int ct = (t >> 6) / NKS;
    int n = lane & 15, quad = lane >> 4;
    int c = ct * 16 + n;
    const float* W = (c < 64) ? Wl : Wr;
    int cc = c & 63;
    u32* d = Wb + (u64)t * 4;
#pragma unroll
    for (int p = 0; p < 4; p++) {
        int k0 = ks * 32 + quad * 8 + 2 * p;
        d[p] = pack2(W[(u64)k0 * 64 + cc], W[(u64)(k0 + 1) * 64 + cc]);
    }
}

// ---------- MFMA dual GEMM: [xl|xr] = X @ [Wl|Wr] + [bl|br] (bf16 out) ----------
template <int K, bool XF32>
__global__ __launch_bounds__(256) void gemm_mfma(const void* __restrict__ Xv,
                                                 const u32* __restrict__ Wb,
                                                 const float* __restrict__ bl,
                                                 const float* __restrict__ br,
                                                 int N, u16* __restrict__ xl, u16* __restrict__ xr) {
    constexpr int NKS = K / 32;
    int lane = threadIdx.x & 63;
    int gw = (blockIdx.x * 256 + threadIdx.x) >> 6;
    int row0 = gw * 16;
    if (row0 >= N) return;
    int m = lane & 15, quad = lane >> 4;

    f32x4 acc[8];
#pragma unroll
    for (int ct = 0; ct < 8; ct++) acc[ct] = (f32x4){0.f, 0.f, 0.f, 0.f};

#pragma unroll
    for (int ks = 0; ks < NKS; ks++) {
        bfrag a;
        if (XF32) {
            const float* xp = (const float*)Xv + (u64)(row0 + m) * K + ks * 32 + quad * 8;
            float4 v0 = *(const float4*)xp;
            float4 v1 = *(const float4*)(xp + 4);
            union { bfrag v; u32 d[4]; } au;
            au.d[0] = pack2(v0.x, v0.y); au.d[1] = pack2(v0.z, v0.w);
            au.d[2] = pack2(v1.x, v1.y); au.d[3] = pack2(v1.z, v1.w);
            a = au.v;
        } else {
            a = *(const bfrag*)((const u16*)Xv + (u64)(row0 + m) * K + ks * 32 + quad * 8);
        }
#pragma unroll
        for (int ct = 0; ct < 8; ct++) {
            bfrag b = *(const bfrag*)(Wb + (u64)((ct * NKS + ks) * 64 + lane) * 4);
            acc[ct] = __builtin_amdgcn_mfma_f32_16x16x32_bf16(a, b, acc[ct], 0, 0, 0);
        }
    }

    // Epilogue: C/D layout col=lane&15(=m), row=quad*4+reg
#pragma unroll
    for (int ct = 0; ct < 8; ct++) {
        float bv = (ct < 4) ? bl[ct * 16 + m] : br[(ct - 4) * 16 + m];
        u16* dbuf = (ct < 4) ? xl : xr;
        int cc = (ct & 3) * 16 + m;
#pragma unroll
        for (int r = 0; r < 4; r++) {
            int row = row0 + quad * 4 + r;
            dbuf[(u64)row * 64 + cc] = f2bf(acc[ct][r] + bv);
        }
    }
}

// ---------- GATv2 layer: wave/node, scalar edge records, DPP head-reduce ----------
template <int RS>
__global__ __launch_bounds__(256) void gat_layer(const u16* __restrict__ xl, const u16* __restrict__ xr,
                                                 const int* __restrict__ offs, const u32* __restrict__ rec,
                                                 const u16* __restrict__ loop_ea,
                                                 const float* __restrict__ We,   // 16 x 64, fp32
                                                 const float* __restrict__ att,  // 64 (= 4x16), fp32
                                                 const float* __restrict__ bias, // 64, fp32
                                                 int N, u16* __restrict__ out) {
    int l = threadIdx.x & 63;            // channel = h*16 + c
    int wid = RFL((int)((blockIdx.x * 256 + threadIdx.x) >> 6));
    int nw = gridDim.x * 4;
    float wec[16];
#pragma unroll
    for (int k = 0; k < 16; k++) wec[k] = We[k * 64 + l];   // We column for this lane
    float att_l = att[l];
    float bias_l = bias[l];
    const u32* le = (const u32*)loop_ea;      // 8 dwords per node

    for (int n = wid; n < N; n += nw) {
        float xr_l = bf2f(xr[(u32)(n * 64 + l)]);
        int a = RFL(offs[n]);
        int b = RFL(offs[n + 1]);
        float lsum = 0.f, o = 0.f;

        auto edge_u = [&](const u32* eap, int srcn) {   // eap -> 8 attr dwords
            float xlv = bf2f(xl[(u32)(srcn * 64 + l)]);
            float z = xr_l;
#pragma unroll
            for (int k = 0; k < 8; k++) {
                u32 u = eap[k];                       // wave-uniform -> s_load, scalar unpack
                z = fmaf(lo16(u), wec[2 * k], z);
                z = fmaf(hi16(u), wec[2 * k + 1], z);
            }
            z += xlv;
            z = fmaxf(z, 0.2f * z);                   // leaky_relu(0.2)
            float w = __expf(red16(z * att_l));       // DPP 16-lane sum, then exp
            lsum += w;
            o = fmaf(w, xlv, o);
        };

        edge_u(le + (u64)n * 8, n);                   // self-loop (mean attrs)
        int i = a;
        for (; i < b - 1; i += 2) {                   // 2x unroll
            const u32* e0 = rec + (u64)i * RS;
            const u32* e1 = rec + (u64)(i + 1) * RS;
            int s0 = RFL((int)e0[0]);
            int s1 = RFL((int)e1[0]);
            edge_u(e0 + 2, s0);
            edge_u(e1 + 2, s1);
        }
        if (i < b) {
            const u32* e0 = rec + (u64)i * RS;
            edge_u(e0 + 2, RFL((int)e0[0]));
        }

        float res = o / (lsum + 1e-16f) + bias_l;
        res = fmaxf(res, 0.f);                        // relu after each GAT layer
        out[(u32)(n * 64 + l)] = f2bf(res);
    }
}

// ---------- MLP head: relu(h @ W1 + b1) @ W2 + b2 -> sigmoid (fp32 out) ----------
__global__ __launch_bounds__(256) void mlp_head(const u16* __restrict__ h,
                                                const float* __restrict__ W1, const float* __restrict__ b1,
                                                const float* __restrict__ W2, const float* __restrict__ b2,
                                                int N, float* __restrict__ out) {
    __shared__ float w1[64 * 16];
    __shared__ float sb1[16];
    __shared__ float w2[16];
    for (int i = threadIdx.x; i < 64 * 16; i += 256) w1[i] = W1[i];
    if (threadIdx.x < 16) { sb1[threadIdx.x] = b1[threadIdx.x]; w2[threadIdx.x] = W2[threadIdx.x]; }
    __syncthreads();
    float b2v = b2[0];
    int n = blockIdx.x * blockDim.x + threadIdx.x;
    if (n < N) {
        float hv[64];
        const u32* hp = (const u32*)(h + (u64)n * 64);
#pragma unroll
        for (int i = 0; i < 32; i++) { u32 u = hp[i]; hv[2 * i] = lo16(u); hv[2 * i + 1] = hi16(u); }
        float z = b2v;
        for (int j = 0; j < 16; j++) {
            float acc = sb1[j];
#pragma unroll
            for (int k = 0; k < 64; k++) acc = fmaf(hv[k], w1[k * 16 + j], acc);
            acc = fmaxf(acc, 0.f);
            z = fmaf(acc, w2[j], z);
        }
        out[n] = 1.f / (1.f + __expf(-z));
    }
}

// ---------- templated pipeline tail (record-stride dependent) ----------
struct Args {
    const float *x, *ea;
    const int *srcv, *dstv;
    const float *Wl1, *bl1, *Wr1, *br1, *We1, *att1, *bias1;
    const float *Wl2, *bl2, *Wr2, *br2, *We2, *att2, *bias2;
    const float *W1, *b1, *W2, *b2;
    float* out;
    int N, E;
    int *deg, *cursor, *offs, *partials;
    u32 *rec, *wb1, *wb2;
    u16 *loop_ea, *xl, *xr, *hb;
};

template <int RS>
static void run_pipeline(const Args& A, hipStream_t stream) {
    const int B = 256;
    int N = A.N, E = A.E;

    hipMemsetAsync(A.deg, 0, (size_t)N * 4, stream);
    pack_w<128><<<8, 256, 0, stream>>>(A.Wl1, A.Wr1, A.wb1);
    pack_w<64><<<4, 256, 0, stream>>>(A.Wl2, A.Wr2, A.wb2);

    deg_hist<<<(E + B - 1) / B, B, 0, stream>>>(A.dstv, E, A.deg);
    int nb = (N + SCAN_CHUNK - 1) / SCAN_CHUNK;
    scan_partial<<<nb, SCAN_T, 0, stream>>>(A.deg, N, A.partials);
    scan_mid<<<1, 64, 0, stream>>>(A.partials, nb);
    scan_final<<<nb, SCAN_T, 0, stream>>>(A.deg, N, A.partials, A.offs, E);
    hipMemcpyAsync(A.cursor, A.offs, (size_t)N * 4, hipMemcpyDeviceToDevice, stream);
    csr_fill_ea<RS><<<(E + B - 1) / B, B, 0, stream>>>(A.srcv, A.dstv, (const float4*)A.ea, E,
                                                       A.cursor, A.rec);
    loop_mean<RS><<<(16 * N + B - 1) / B, B, 0, stream>>>(A.offs, (const u16*)A.rec, N, A.loop_ea);

    int gemm_blocks = (N / 16 + 3) / 4;
    gemm_mfma<128, true><<<gemm_blocks, 256, 0, stream>>>(A.x, A.wb1, A.bl1, A.br1, N, A.xl, A.xr);
    gat_layer<RS><<<8192, 256, 0, stream>>>(A.xl, A.xr, A.offs, A.rec, A.loop_ea,
                                            A.We1, A.att1, A.bias1, N, A.hb);
    gemm_mfma<64, false><<<gemm_blocks, 256, 0, stream>>>(A.hb, A.wb2, A.bl2, A.br2, N, A.xl, A.xr);
    gat_layer<RS><<<8192, 256, 0, stream>>>(A.xl, A.xr, A.offs, A.rec, A.loop_ea,
                                            A.We2, A.att2, A.bias2, N, A.hb);
    mlp_head<<<(N + B - 1) / B, B, 0, stream>>>(A.hb, A.W1, A.b1, A.W2, A.b2, N, A.out);
}

// ---------- launch ----------
extern "C" void kernel_launch(void* const* d_in, const int* in_sizes, int n_in,
                              void* d_out, int out_size, void* d_ws, size_t ws_size,
                              hipStream_t stream) {
    Args A;
    A.x    = (const float*)d_in[0];
    const int* ei = (const int*)d_in[1];
    A.ea   = (const float*)d_in[2];
    A.Wl1  = (const float*)d_in[3];  A.bl1 = (const float*)d_in[4];
    A.Wr1  = (const float*)d_in[5];  A.br1 = (const float*)d_in[6];
    A.We1  = (const float*)d_in[7];  A.att1 = (const float*)d_in[8];  A.bias1 = (const float*)d_in[9];
    A.Wl2  = (const float*)d_in[10]; A.bl2 = (const float*)d_in[11];
    A.Wr2  = (const float*)d_in[12]; A.br2 = (const float*)d_in[13];
    A.We2  = (const float*)d_in[14]; A.att2 = (const float*)d_in[15]; A.bias2 = (const float*)d_in[16];
    A.W1   = (const float*)d_in[17]; A.b1 = (const float*)d_in[18];
    A.W2   = (const float*)d_in[19]; A.b2 = (const float*)d_in[20];
    A.out  = (float*)d_out;

    A.N = in_sizes[0] / 128;
    A.E = in_sizes[1] / 2;
    A.srcv = ei;
    A.dstv = ei + A.E;
    const int N = A.N, E = A.E;

    // need for RS=16 path (with margin for carve rounding)
    size_t need16 = (size_t)E * 64 + (size_t)N * (4 + 4 + 4 + 32 + 128 + 128 + 128) + (1u << 21);
    int RS = (ws_size >= need16) ? 16 : 10;

    uint8_t* p = (uint8_t*)d_ws;
    auto carve = [&](size_t bytes) -> void* {
        void* r = (void*)p;
        p += (bytes + 255) & ~(size_t)255;
        return r;
    };
    A.deg     = (int*)carve((size_t)N * 4);
    A.cursor  = (int*)carve((size_t)N * 4);
    A.offs    = (int*)carve((size_t)(N + 1) * 4);
    A.partials= (int*)carve(4096);
    A.rec     = (u32*)carve((size_t)E * 4 * RS);
    A.loop_ea = (u16*)carve((size_t)N * 16 * 2);
    A.xl      = (u16*)carve((size_t)N * 64 * 2);
    A.xr      = (u16*)carve((size_t)N * 64 * 2);
    A.hb      = (u16*)carve((size_t)N * 64 * 2);
    A.wb1     = (u32*)carve(8 * 4 * 64 * 16);   // K=128 packed W
    A.wb2     = (u32*)carve(8 * 2 * 64 * 16);   // K=64 packed W
    (void)ws_size; (void)n_in; (void)out_size;

    if (RS == 16) run_pipeline<16>(A, stream);
    else          run_pipeline<10>(A, stream);
}

// Round 8
// 637.822 us; speedup vs baseline: 1.2189x; 1.0173x over previous
//
#include <hip/hip_runtime.h>
#include <stdint.h>

typedef unsigned short u16;
typedef unsigned int u32;
typedef unsigned long long u64;

typedef __attribute__((ext_vector_type(8))) short bfrag;   // 8 bf16 (4 VGPRs)
typedef __attribute__((ext_vector_type(4))) float f32x4;   // 4 fp32 acc

#if __has_builtin(__builtin_amdgcn_fdot2_f32_bf16)
#define HAS_DOT2 1
typedef __attribute__((ext_vector_type(2))) __bf16 bf16x2;
#else
#define HAS_DOT2 0
#endif

// ---------- bf16 helpers (OCP bf16 = raw upper 16 bits of fp32) ----------
__device__ __forceinline__ float bf2f(u16 u) { return __uint_as_float(((u32)u) << 16); }
__device__ __forceinline__ u16 f2bf(float f) {
    u32 i = __float_as_uint(f);
    u32 r = i + 0x7fffu + ((i >> 16) & 1u);   // round-to-nearest-even
    return (u16)(r >> 16);
}
__device__ __forceinline__ float lo16(u32 u) { return __uint_as_float(u << 16); }
__device__ __forceinline__ float hi16(u32 u) { return __uint_as_float(u & 0xffff0000u); }
__device__ __forceinline__ u32 pack2(float a, float b) {
    return (u32)f2bf(a) | ((u32)f2bf(b) << 16);
}
#define RFL(x) __builtin_amdgcn_readfirstlane(x)

// 16-lane (row) sum via DPP row_ror rotate-adds: 4 dependent v_add_f32, no LDS pipe.
#define DPP_ROR_ADD(p, ctrl) \
    p += __int_as_float(__builtin_amdgcn_update_dpp(0, __float_as_int(p), ctrl, 0xF, 0xF, false))
__device__ __forceinline__ float red16(float p) {
    DPP_ROR_ADD(p, 0x128);   // ror 8
    DPP_ROR_ADD(p, 0x124);   // ror 4
    DPP_ROR_ADD(p, 0x122);   // ror 2
    DPP_ROR_ADD(p, 0x121);   // ror 1
    return p;                // every lane in the 16-row holds the row sum
}

// ---------- CSR build ----------
__global__ void deg_hist(const int* __restrict__ dst, int E, int* __restrict__ deg) {
    int e = blockIdx.x * blockDim.x + threadIdx.x;
    if (e < E) atomicAdd(&deg[dst[e]], 1);
}

#define SCAN_T 256
#define SCAN_E 8
#define SCAN_CHUNK 2048

__global__ void scan_partial(const int* __restrict__ deg, int n, int* __restrict__ partials) {
    __shared__ int sh[SCAN_T];
    int b = blockIdx.x, t = threadIdx.x;
    int base = b * SCAN_CHUNK + t * SCAN_E;
    int s = 0;
#pragma unroll
    for (int i = 0; i < SCAN_E; i++) { int idx = base + i; if (idx < n) s += deg[idx]; }
    sh[t] = s; __syncthreads();
    for (int off = SCAN_T / 2; off > 0; off >>= 1) {
        if (t < off) sh[t] += sh[t + off];
        __syncthreads();
    }
    if (t == 0) partials[b] = sh[0];
}

__global__ void scan_mid(int* __restrict__ partials, int nb) {
    if (threadIdx.x == 0 && blockIdx.x == 0) {
        int acc = 0;
        for (int i = 0; i < nb; i++) { int v = partials[i]; partials[i] = acc; acc += v; }
    }
}

__global__ void scan_final(const int* __restrict__ deg, int n, const int* __restrict__ partials,
                           int* __restrict__ offs, int E) {
    __shared__ int sh[SCAN_T];
    int b = blockIdx.x, t = threadIdx.x;
    int base = b * SCAN_CHUNK + t * SCAN_E;
    int loc[SCAN_E];
    int s = 0;
#pragma unroll
    for (int i = 0; i < SCAN_E; i++) {
        int idx = base + i;
        int v = (idx < n) ? deg[idx] : 0;
        loc[i] = s; s += v;
    }
    sh[t] = s; __syncthreads();
    for (int off = 1; off < SCAN_T; off <<= 1) {
        int v = 0;
        if (t >= off) v = sh[t - off];
        __syncthreads();
        if (t >= off) sh[t] += v;
        __syncthreads();
    }
    int tbase = partials[b] + sh[t] - s;   // exclusive base for this thread
#pragma unroll
    for (int i = 0; i < SCAN_E; i++) { int idx = base + i; if (idx < n) offs[idx] = tbase + loc[i]; }
    if (b == gridDim.x - 1 && t == SCAN_T - 1) offs[n] = E;
}

// ---------- fused CSR fill: one 64B (or 40B) record per edge = src + bf16 attrs ----------
// record dwords: [0]=src [1]=pad [2..9]=16 bf16 attrs [10..RS) = pad
template <int RS>
__global__ void csr_fill_ea(const int* __restrict__ srcv, const int* __restrict__ dstv,
                            const float4* __restrict__ ea, int E,
                            int* __restrict__ cursor, u32* __restrict__ rec) {
    int e = blockIdx.x * blockDim.x + threadIdx.x;
    if (e >= E) return;
    const float4* s = ea + (u64)e * 4;
    float4 v0 = s[0], v1 = s[1], v2 = s[2], v3 = s[3];
    u32 a0 = pack2(v0.x, v0.y), a1 = pack2(v0.z, v0.w);
    u32 a2 = pack2(v1.x, v1.y), a3 = pack2(v1.z, v1.w);
    u32 a4 = pack2(v2.x, v2.y), a5 = pack2(v2.z, v2.w);
    u32 a6 = pack2(v3.x, v3.y), a7 = pack2(v3.z, v3.w);
    int sr = srcv[e];
    int d = dstv[e];
    int p = atomicAdd(&cursor[d], 1);
    u32* r = rec + (u64)p * RS;
    if (RS == 16) {              // full-cacheline record: clean 64B line write, no RMW
        uint4* q = (uint4*)r;
        q[0] = make_uint4((u32)sr, 0u, a0, a1);
        q[1] = make_uint4(a2, a3, a4, a5);
        q[2] = make_uint4(a6, a7, 0u, 0u);
        q[3] = make_uint4(0u, 0u, 0u, 0u);
    } else {                     // 40B record (8B-aligned), smaller footprint
        u64* q = (u64*)r;
        q[0] = (u64)(u32)sr;
        q[1] = (u64)a0 | ((u64)a1 << 32);
        q[2] = (u64)a2 | ((u64)a3 << 32);
        q[3] = (u64)a4 | ((u64)a5 << 32);
        q[4] = (u64)a6 | ((u64)a7 << 32);
    }
}

// ---------- W pre-pack: Wl,Wr (fp32, K x 64 each) -> bf16 B-fragment order ----------
template <int K>
__global__ void pack_w(const float* __restrict__ Wl, const float* __restrict__ Wr,
                       u32* __restrict__ Wb) {
    constexpr int NKS = K / 32;
    int t = blockIdx.x * blockDim.x + threadIdx.x;
    if (t >= 8 * NKS * 64) return;
    int lane = t & 63;
    int ks = (t >> 6) % NKS;
    int ct = (t >> 6) / NKS;
    int n = lane & 15, quad = lane >> 4;
    int c = ct * 16 + n;
    const float* W = (c < 64) ? Wl : Wr;
    int cc = c & 63;
    u32* d = Wb + (u64)t * 4;
#pragma unroll
    for (int p = 0; p < 4; p++) {
        int k0 = ks * 32 + quad * 8 + 2 * p;
        d[p] = pack2(W[(u64)k0 * 64 + cc], W[(u64)(k0 + 1) * 64 + cc]);
    }
}

// ---------- MFMA dual GEMM: [xl|xr] = X @ [Wl|Wr] + [bl|br] (bf16 out) ----------
template <int K, bool XF32>
__global__ __launch_bounds__(256) void gemm_mfma(const void* __restrict__ Xv,
                                                 const u32* __restrict__ Wb,
                                                 const float* __restrict__ bl,
                                                 const float* __restrict__ br,
                                                 int N, u16* __restrict__ xl, u16* __restrict__ xr) {
    constexpr int NKS = K / 32;
    int lane = threadIdx.x & 63;
    int gw = (blockIdx.x * 256 + threadIdx.x) >> 6;
    int row0 = gw * 16;
    if (row0 >= N) return;
    int m = lane & 15, quad = lane >> 4;

    f32x4 acc[8];
#pragma unroll
    for (int ct = 0; ct < 8; ct++) acc[ct] = (f32x4){0.f, 0.f, 0.f, 0.f};

#pragma unroll
    for (int ks = 0; ks < NKS; ks++) {
        bfrag a;
        if (XF32) {
            const float* xp = (const float*)Xv + (u64)(row0 + m) * K + ks * 32 + quad * 8;
            float4 v0 = *(const float4*)xp;
            float4 v1 = *(const float4*)(xp + 4);
            union { bfrag v; u32 d[4]; } au;
            au.d[0] = pack2(v0.x, v0.y); au.d[1] = pack2(v0.z, v0.w);
            au.d[2] = pack2(v1.x, v1.y); au.d[3] = pack2(v1.z, v1.w);
            a = au.v;
        } else {
            a = *(const bfrag*)((const u16*)Xv + (u64)(row0 + m) * K + ks * 32 + quad * 8);
        }
#pragma unroll
        for (int ct = 0; ct < 8; ct++) {
            bfrag b = *(const bfrag*)(Wb + (u64)((ct * NKS + ks) * 64 + lane) * 4);
            acc[ct] = __builtin_amdgcn_mfma_f32_16x16x32_bf16(a, b, acc[ct], 0, 0, 0);
        }
    }

    // Epilogue: C/D layout col=lane&15(=m), row=quad*4+reg
#pragma unroll
    for (int ct = 0; ct < 8; ct++) {
        float bv = (ct < 4) ? bl[ct * 16 + m] : br[(ct - 4) * 16 + m];
        u16* dbuf = (ct < 4) ? xl : xr;
        int cc = (ct & 3) * 16 + m;
#pragma unroll
        for (int r = 0; r < 4; r++) {
            int row = row0 + quad * 4 + r;
            dbuf[(u64)row * 64 + cc] = f2bf(acc[ct][r] + bv);
        }
    }
}

// ---------- GATv2 layer ----------
// Self-loop handled via linearity: mean(ea)@We == mean(ea@We) == eesum/deg,
// accumulated in-register during the edge loop (no loop_mean pass, no loop_ea buffer).
template <int RS>
__global__ __launch_bounds__(256) void gat_layer(const u16* __restrict__ xl, const u16* __restrict__ xr,
                                                 const int* __restrict__ offs, const u32* __restrict__ rec,
                                                 const float* __restrict__ We,   // 16 x 64, fp32
                                                 const float* __restrict__ att,  // 64 (= 4x16), fp32
                                                 const float* __restrict__ bias, // 64, fp32
                                                 int N, u16* __restrict__ out) {
    int l = threadIdx.x & 63;            // channel = h*16 + c
    int wid = RFL((int)((blockIdx.x * 256 + threadIdx.x) >> 6));
    int nw = gridDim.x * 4;
#if HAS_DOT2
    bf16x2 wec[8];                       // We column, packed bf16 pairs (8 VGPRs)
#pragma unroll
    for (int k = 0; k < 8; k++) {
        union { u32 u; bf16x2 v; } wu;
        wu.u = pack2(We[(2 * k) * 64 + l], We[(2 * k + 1) * 64 + l]);
        wec[k] = wu.v;
    }
#else
    float wec[16];
#pragma unroll
    for (int k = 0; k < 16; k++) wec[k] = We[k * 64 + l];
#endif
    float att_l = att[l];
    float bias_l = bias[l];

    for (int n = wid; n < N; n += nw) {
        float xr_l = bf2f(xr[(u32)(n * 64 + l)]);
        float xl_self = bf2f(xl[(u32)(n * 64 + l)]);
        int a = RFL(offs[n]);
        int b = RFL(offs[n + 1]);
        float lsum = 0.f, o = 0.f, eesum = 0.f;

        auto edge_u = [&](const u32* eap, int srcn) {   // eap -> 8 attr dwords
            float xlv = bf2f(xl[(u32)(srcn * 64 + l)]);
            float ee = 0.f;
#if HAS_DOT2
#pragma unroll
            for (int k = 0; k < 8; k++) {
                union { u32 u; bf16x2 v; } au;
                au.u = eap[k];
                ee = __builtin_amdgcn_fdot2_f32_bf16(au.v, wec[k], ee, false);
            }
#else
#pragma unroll
            for (int k = 0; k < 8; k++) {
                u32 u = eap[k];
                ee = fmaf(lo16(u), wec[2 * k], ee);
                ee = fmaf(hi16(u), wec[2 * k + 1], ee);
            }
#endif
            eesum += ee;
            float z = (ee + xr_l) + xlv;
            z = fmaxf(z, 0.2f * z);                   // leaky_relu(0.2)
            float w = __expf(red16(z * att_l));       // DPP 16-lane sum, then exp
            lsum += w;
            o = fmaf(w, xlv, o);
        };

        int i = a;
        for (; i < b - 1; i += 2) {                   // 2x unroll
            const u32* e0 = rec + (u64)i * RS;
            const u32* e1 = rec + (u64)(i + 1) * RS;
            int s0 = RFL((int)e0[0]);
            int s1 = RFL((int)e1[0]);
            edge_u(e0 + 2, s0);
            edge_u(e1 + 2, s1);
        }
        if (i < b) {
            const u32* e0 = rec + (u64)i * RS;
            edge_u(e0 + 2, RFL((int)e0[0]));
        }

        { // self-loop: ee = eesum/deg (mean edge attr transform), src = n
            int deg = b - a;
            float inv = (deg > 0) ? 1.f / (float)deg : 0.f;
            float z = (eesum * inv + xr_l) + xl_self;
            z = fmaxf(z, 0.2f * z);
            float w = __expf(red16(z * att_l));
            lsum += w;
            o = fmaf(w, xl_self, o);
        }

        float res = o / (lsum + 1e-16f) + bias_l;
        res = fmaxf(res, 0.f);                        // relu after each GAT layer
        out[(u32)(n * 64 + l)] = f2bf(res);
    }
}

// ---------- MLP head: relu(h @ W1 + b1) @ W2 + b2 -> sigmoid (fp32 out) ----------
__global__ __launch_bounds__(256) void mlp_head(const u16* __restrict__ h,
                                                const float* __restrict__ W1, const float* __restrict__ b1,
                                                const float* __restrict__ W2, const float* __restrict__ b2,
                                                int N, float* __restrict__ out) {
    __shared__ float w1[64 * 16];
    __shared__ float sb1[16];
    __shared__ float w2[16];
    for (int i = threadIdx.x; i < 64 * 16; i += 256) w1[i] = W1[i];
    if (threadIdx.x < 16) { sb1[threadIdx.x] = b1[threadIdx.x]; w2[threadIdx.x] = W2[threadIdx.x]; }
    __syncthreads();
    float b2v = b2[0];
    int n = blockIdx.x * blockDim.x + threadIdx.x;
    if (n < N) {
        float hv[64];
        const u32* hp = (const u32*)(h + (u64)n * 64);
#pragma unroll
        for (int i = 0; i < 32; i++) { u32 u = hp[i]; hv[2 * i] = lo16(u); hv[2 * i + 1] = hi16(u); }
        float z = b2v;
        for (int j = 0; j < 16; j++) {
            float acc = sb1[j];
#pragma unroll
            for (int k = 0; k < 64; k++) acc = fmaf(hv[k], w1[k * 16 + j], acc);
            acc = fmaxf(acc, 0.f);
            z = fmaf(acc, w2[j], z);
        }
        out[n] = 1.f / (1.f + __expf(-z));
    }
}

// ---------- templated pipeline tail (record-stride dependent) ----------
struct Args {
    const float *x, *ea;
    const int *srcv, *dstv;
    const float *Wl1, *bl1, *Wr1, *br1, *We1, *att1, *bias1;
    const float *Wl2, *bl2, *Wr2, *br2, *We2, *att2, *bias2;
    const float *W1, *b1, *W2, *b2;
    float* out;
    int N, E;
    int *deg, *cursor, *offs, *partials;
    u32 *rec, *wb1, *wb2;
    u16 *xl, *xr, *hb;
};

template <int RS>
static void run_pipeline(const Args& A, hipStream_t stream) {
    const int B = 256;
    int N = A.N, E = A.E;

    hipMemsetAsync(A.deg, 0, (size_t)N * 4, stream);
    pack_w<128><<<8, 256, 0, stream>>>(A.Wl1, A.Wr1, A.wb1);
    pack_w<64><<<4, 256, 0, stream>>>(A.Wl2, A.Wr2, A.wb2);

    deg_hist<<<(E + B - 1) / B, B, 0, stream>>>(A.dstv, E, A.deg);
    int nb = (N + SCAN_CHUNK - 1) / SCAN_CHUNK;
    scan_partial<<<nb, SCAN_T, 0, stream>>>(A.deg, N, A.partials);
    scan_mid<<<1, 64, 0, stream>>>(A.partials, nb);
    scan_final<<<nb, SCAN_T, 0, stream>>>(A.deg, N, A.partials, A.offs, E);
    hipMemcpyAsync(A.cursor, A.offs, (size_t)N * 4, hipMemcpyDeviceToDevice, stream);
    csr_fill_ea<RS><<<(E + B - 1) / B, B, 0, stream>>>(A.srcv, A.dstv, (const float4*)A.ea, E,
                                                       A.cursor, A.rec);

    int gemm_blocks = (N / 16 + 3) / 4;
    gemm_mfma<128, true><<<gemm_blocks, 256, 0, stream>>>(A.x, A.wb1, A.bl1, A.br1, N, A.xl, A.xr);
    gat_layer<RS><<<8192, 256, 0, stream>>>(A.xl, A.xr, A.offs, A.rec,
                                            A.We1, A.att1, A.bias1, N, A.hb);
    gemm_mfma<64, false><<<gemm_blocks, 256, 0, stream>>>(A.hb, A.wb2, A.bl2, A.br2, N, A.xl, A.xr);
    gat_layer<RS><<<8192, 256, 0, stream>>>(A.xl, A.xr, A.offs, A.rec,
                                            A.We2, A.att2, A.bias2, N, A.hb);
    mlp_head<<<(N + B - 1) / B, B, 0, stream>>>(A.hb, A.W1, A.b1, A.W2, A.b2, N, A.out);
}

// ---------- launch ----------
extern "C" void kernel_launch(void* const* d_in, const int* in_sizes, int n_in,
                              void* d_out, int out_size, void* d_ws, size_t ws_size,
                              hipStream_t stream) {
    Args A;
    A.x    = (const float*)d_in[0];
    const int* ei = (const int*)d_in[1];
    A.ea   = (const float*)d_in[2];
    A.Wl1  = (const float*)d_in[3];  A.bl1 = (const float*)d_in[4];
    A.Wr1  = (const float*)d_in[5];  A.br1 = (const float*)d_in[6];
    A.We1  = (const float*)d_in[7];  A.att1 = (const float*)d_in[8];  A.bias1 = (const float*)d_in[9];
    A.Wl2  = (const float*)d_in[10]; A.bl2 = (const float*)d_in[11];
    A.Wr2  = (const float*)d_in[12]; A.br2 = (const float*)d_in[13];
    A.We2  = (const float*)d_in[14]; A.att2 = (const float*)d_in[15]; A.bias2 = (const float*)d_in[16];
    A.W1   = (const float*)d_in[17]; A.b1 = (const float*)d_in[18];
    A.W2   = (const float*)d_in[19]; A.b2 = (const float*)d_in[20];
    A.out  = (float*)d_out;

    A.N = in_sizes[0] / 128;
    A.E = in_sizes[1] / 2;
    A.srcv = ei;
    A.dstv = ei + A.E;
    const int N = A.N, E = A.E;

    // need for RS=16 path (with margin for carve rounding)
    size_t need16 = (size_t)E * 64 + (size_t)N * (4 + 4 + 4 + 128 + 128 + 128) + (1u << 21);
    int RS = (ws_size >= need16) ? 16 : 10;

    uint8_t* p = (uint8_t*)d_ws;
    auto carve = [&](size_t bytes) -> void* {
        void* r = (void*)p;
        p += (bytes + 255) & ~(size_t)255;
        return r;
    };
    A.deg     = (int*)carve((size_t)N * 4);
    A.cursor  = (int*)carve((size_t)N * 4);
    A.offs    = (int*)carve((size_t)(N + 1) * 4);
    A.partials= (int*)carve(4096);
    A.rec     = (u32*)carve((size_t)E * 4 * RS);
    A.xl      = (u16*)carve((size_t)N * 64 * 2);
    A.xr      = (u16*)carve((size_t)N * 64 * 2);
    A.hb      = (u16*)carve((size_t)N * 64 * 2);
    A.wb1     = (u32*)carve(8 * 4 * 64 * 16);   // K=128 packed W
    A.wb2     = (u32*)carve(8 * 2 * 64 * 16);   // K=64 packed W
    (void)ws_size; (void)n_in; (void)out_size;

    if (RS == 16) run_pipeline<16>(A, stream);
    else          run_pipeline<10>(A, stream);
}

// Round 9
// 635.229 us; speedup vs baseline: 1.2239x; 1.0041x over previous
//
#include <hip/hip_runtime.h>
#include <stdint.h>

typedef unsigned short u16;
typedef unsigned int u32;
typedef unsigned long long u64;

typedef __attribute__((ext_vector_type(8))) short bfrag;   // 8 bf16 (4 VGPRs)
typedef __attribute__((ext_vector_type(4))) float f32x4;   // 4 fp32 acc

// ---------- bf16 helpers (OCP bf16 = raw upper 16 bits of fp32) ----------
__device__ __forceinline__ float bf2f(u16 u) { return __uint_as_float(((u32)u) << 16); }
__device__ __forceinline__ u16 f2bf(float f) {
    u32 i = __float_as_uint(f);
    u32 r = i + 0x7fffu + ((i >> 16) & 1u);   // round-to-nearest-even
    return (u16)(r >> 16);
}
__device__ __forceinline__ float lo16(u32 u) { return __uint_as_float(u << 16); }
__device__ __forceinline__ float hi16(u32 u) { return __uint_as_float(u & 0xffff0000u); }
__device__ __forceinline__ u32 pack2(float a, float b) {
    return (u32)f2bf(a) | ((u32)f2bf(b) << 16);
}
#define RFL(x) __builtin_amdgcn_readfirstlane(x)

// 16-lane (row) sum via DPP row_ror rotate-adds: 4 dependent v_add_f32, no LDS pipe.
#define DPP_ROR_ADD(p, ctrl) \
    p += __int_as_float(__builtin_amdgcn_update_dpp(0, __float_as_int(p), ctrl, 0xF, 0xF, false))
__device__ __forceinline__ float red16(float p) {
    DPP_ROR_ADD(p, 0x128);   // ror 8
    DPP_ROR_ADD(p, 0x124);   // ror 4
    DPP_ROR_ADD(p, 0x122);   // ror 2
    DPP_ROR_ADD(p, 0x121);   // ror 1
    return p;                // every lane in the 16-row holds the row sum
}

// ---------- CSR build ----------
__global__ void deg_hist(const int* __restrict__ dst, int E, int* __restrict__ deg) {
    int e = blockIdx.x * blockDim.x + threadIdx.x;
    if (e < E) atomicAdd(&deg[dst[e]], 1);
}

#define SCAN_T 256
#define SCAN_E 8
#define SCAN_CHUNK 2048

__global__ void scan_partial(const int* __restrict__ deg, int n, int* __restrict__ partials) {
    __shared__ int sh[SCAN_T];
    int b = blockIdx.x, t = threadIdx.x;
    int base = b * SCAN_CHUNK + t * SCAN_E;
    int s = 0;
#pragma unroll
    for (int i = 0; i < SCAN_E; i++) { int idx = base + i; if (idx < n) s += deg[idx]; }
    sh[t] = s; __syncthreads();
    for (int off = SCAN_T / 2; off > 0; off >>= 1) {
        if (t < off) sh[t] += sh[t + off];
        __syncthreads();
    }
    if (t == 0) partials[b] = sh[0];
}

__global__ void scan_mid(int* __restrict__ partials, int nb) {
    if (threadIdx.x == 0 && blockIdx.x == 0) {
        int acc = 0;
        for (int i = 0; i < nb; i++) { int v = partials[i]; partials[i] = acc; acc += v; }
    }
}

__global__ void scan_final(const int* __restrict__ deg, int n, const int* __restrict__ partials,
                           int* __restrict__ offs, int E) {
    __shared__ int sh[SCAN_T];
    int b = blockIdx.x, t = threadIdx.x;
    int base = b * SCAN_CHUNK + t * SCAN_E;
    int loc[SCAN_E];
    int s = 0;
#pragma unroll
    for (int i = 0; i < SCAN_E; i++) {
        int idx = base + i;
        int v = (idx < n) ? deg[idx] : 0;
        loc[i] = s; s += v;
    }
    sh[t] = s; __syncthreads();
    for (int off = 1; off < SCAN_T; off <<= 1) {
        int v = 0;
        if (t >= off) v = sh[t - off];
        __syncthreads();
        if (t >= off) sh[t] += v;
        __syncthreads();
    }
    int tbase = partials[b] + sh[t] - s;   // exclusive base for this thread
#pragma unroll
    for (int i = 0; i < SCAN_E; i++) { int idx = base + i; if (idx < n) offs[idx] = tbase + loc[i]; }
    if (b == gridDim.x - 1 && t == SCAN_T - 1) offs[n] = E;
}

// ---------- fused CSR fill, split arrays: src[p] (4B) + attr[p] (32B packed bf16) ----------
__global__ void csr_fill_split(const int* __restrict__ srcv, const int* __restrict__ dstv,
                               const float4* __restrict__ ea, int E,
                               int* __restrict__ cursor,
                               int* __restrict__ csrc, uint4* __restrict__ cattr) {
    int e = blockIdx.x * blockDim.x + threadIdx.x;
    if (e >= E) return;
    const float4* s = ea + (u64)e * 4;
    float4 v0 = s[0], v1 = s[1], v2 = s[2], v3 = s[3];
    uint4 q0 = make_uint4(pack2(v0.x, v0.y), pack2(v0.z, v0.w),
                          pack2(v1.x, v1.y), pack2(v1.z, v1.w));
    uint4 q1 = make_uint4(pack2(v2.x, v2.y), pack2(v2.z, v2.w),
                          pack2(v3.x, v3.y), pack2(v3.z, v3.w));
    int sr = srcv[e];
    int d = dstv[e];
    int p = atomicAdd(&cursor[d], 1);
    csrc[p] = sr;
    cattr[(u64)p * 2] = q0;
    cattr[(u64)p * 2 + 1] = q1;
}

// ---------- W pre-pack: Wl,Wr (fp32, K x 64 each) -> bf16 B-fragment order ----------
template <int K>
__global__ void pack_w(const float* __restrict__ Wl, const float* __restrict__ Wr,
                       u32* __restrict__ Wb) {
    constexpr int NKS = K / 32;
    int t = blockIdx.x * blockDim.x + threadIdx.x;
    if (t >= 8 * NKS * 64) return;
    int lane = t & 63;
    int ks = (t >> 6) % NKS;
    int ct = (t >> 6) / NKS;
    int n = lane & 15, quad = lane >> 4;
    int c = ct * 16 + n;
    const float* W = (c < 64) ? Wl : Wr;
    int cc = c & 63;
    u32* d = Wb + (u64)t * 4;
#pragma unroll
    for (int p = 0; p < 4; p++) {
        int k0 = ks * 32 + quad * 8 + 2 * p;
        d[p] = pack2(W[(u64)k0 * 64 + cc], W[(u64)(k0 + 1) * 64 + cc]);
    }
}

// ---------- MFMA dual GEMM: [xl|xr] = X @ [Wl|Wr] + [bl|br] (bf16 out) ----------
template <int K, bool XF32>
__global__ __launch_bounds__(256) void gemm_mfma(const void* __restrict__ Xv,
                                                 const u32* __restrict__ Wb,
                                                 const float* __restrict__ bl,
                                                 const float* __restrict__ br,
                                                 int N, u16* __restrict__ xl, u16* __restrict__ xr) {
    constexpr int NKS = K / 32;
    int lane = threadIdx.x & 63;
    int gw = (blockIdx.x * 256 + threadIdx.x) >> 6;
    int row0 = gw * 16;
    if (row0 >= N) return;
    int m = lane & 15, quad = lane >> 4;

    f32x4 acc[8];
#pragma unroll
    for (int ct = 0; ct < 8; ct++) acc[ct] = (f32x4){0.f, 0.f, 0.f, 0.f};

#pragma unroll
    for (int ks = 0; ks < NKS; ks++) {
        bfrag a;
        if (XF32) {
            const float* xp = (const float*)Xv + (u64)(row0 + m) * K + ks * 32 + quad * 8;
            float4 v0 = *(const float4*)xp;
            float4 v1 = *(const float4*)(xp + 4);
            union { bfrag v; u32 d[4]; } au;
            au.d[0] = pack2(v0.x, v0.y); au.d[1] = pack2(v0.z, v0.w);
            au.d[2] = pack2(v1.x, v1.y); au.d[3] = pack2(v1.z, v1.w);
            a = au.v;
        } else {
            a = *(const bfrag*)((const u16*)Xv + (u64)(row0 + m) * K + ks * 32 + quad * 8);
        }
#pragma unroll
        for (int ct = 0; ct < 8; ct++) {
            bfrag b = *(const bfrag*)(Wb + (u64)((ct * NKS + ks) * 64 + lane) * 4);
            acc[ct] = __builtin_amdgcn_mfma_f32_16x16x32_bf16(a, b, acc[ct], 0, 0, 0);
        }
    }

    // Epilogue: C/D layout col=lane&15(=m), row=quad*4+reg
#pragma unroll
    for (int ct = 0; ct < 8; ct++) {
        float bv = (ct < 4) ? bl[ct * 16 + m] : br[(ct - 4) * 16 + m];
        u16* dbuf = (ct < 4) ? xl : xr;
        int cc = (ct & 3) * 16 + m;
#pragma unroll
        for (int r = 0; r < 4; r++) {
            int row = row0 + quad * 4 + r;
            dbuf[(u64)row * 64 + cc] = f2bf(acc[ct][r] + bv);
        }
    }
}

// ---------- GATv2 layer: wave/node, split CSR arrays, fma+scalar-unpack ee, DPP reduce ----------
// Self-loop via linearity: mean(ea)@We == eesum/deg, accumulated in-register.
__global__ __launch_bounds__(256) void gat_layer(const u16* __restrict__ xl, const u16* __restrict__ xr,
                                                 const int* __restrict__ offs,
                                                 const int* __restrict__ csrc,   // src per CSR slot
                                                 const u32* __restrict__ cattr,  // 8 dwords per slot
                                                 const float* __restrict__ We,   // 16 x 64, fp32
                                                 const float* __restrict__ att,  // 64 (= 4x16), fp32
                                                 const float* __restrict__ bias, // 64, fp32
                                                 int N, u16* __restrict__ out) {
    int l = threadIdx.x & 63;            // channel = h*16 + c
    int wid = RFL((int)((blockIdx.x * 256 + threadIdx.x) >> 6));
    int nw = gridDim.x * 4;
    float wec[16];
#pragma unroll
    for (int k = 0; k < 16; k++) wec[k] = We[k * 64 + l];   // We column for this lane
    float att_l = att[l];
    float bias_l = bias[l];

    for (int n = wid; n < N; n += nw) {
        float xr_l = bf2f(xr[(u32)(n * 64 + l)]);
        float xl_self = bf2f(xl[(u32)(n * 64 + l)]);
        int a = RFL(offs[n]);
        int b = RFL(offs[n + 1]);
        float lsum = 0.f, o = 0.f, eesum = 0.f;

        auto edge_u = [&](const u32* eap, int srcn) {   // eap -> 8 attr dwords (wave-uniform)
            float xlv = bf2f(xl[(u32)(srcn * 64 + l)]);
            float ee = 0.f;
#pragma unroll
            for (int k = 0; k < 8; k++) {
                u32 u = eap[k];                       // uniform -> s_load, scalar unpack
                ee = fmaf(lo16(u), wec[2 * k], ee);
                ee = fmaf(hi16(u), wec[2 * k + 1], ee);
            }
            eesum += ee;
            float z = (ee + xr_l) + xlv;
            z = fmaxf(z, 0.2f * z);                   // leaky_relu(0.2)
            float w = __expf(red16(z * att_l));       // DPP 16-lane sum, then exp
            lsum += w;
            o = fmaf(w, xlv, o);
        };

        int i = a;
        for (; i < b - 1; i += 2) {                   // 2x unroll
            int s0 = RFL(csrc[i]);
            int s1 = RFL(csrc[i + 1]);
            edge_u(cattr + (u64)i * 8, s0);
            edge_u(cattr + (u64)(i + 1) * 8, s1);
        }
        if (i < b) edge_u(cattr + (u64)i * 8, RFL(csrc[i]));

        { // self-loop: ee = eesum/deg (mean edge-attr transform), src = n
            int deg = b - a;
            float inv = (deg > 0) ? 1.f / (float)deg : 0.f;
            float z = (eesum * inv + xr_l) + xl_self;
            z = fmaxf(z, 0.2f * z);
            float w = __expf(red16(z * att_l));
            lsum += w;
            o = fmaf(w, xl_self, o);
        }

        float res = o / (lsum + 1e-16f) + bias_l;
        res = fmaxf(res, 0.f);                        // relu after each GAT layer
        out[(u32)(n * 64 + l)] = f2bf(res);
    }
}

// ---------- MLP head: relu(h @ W1 + b1) @ W2 + b2 -> sigmoid (fp32 out) ----------
__global__ __launch_bounds__(256) void mlp_head(const u16* __restrict__ h,
                                                const float* __restrict__ W1, const float* __restrict__ b1,
                                                const float* __restrict__ W2, const float* __restrict__ b2,
                                                int N, float* __restrict__ out) {
    __shared__ float w1[64 * 16];
    __shared__ float sb1[16];
    __shared__ float w2[16];
    for (int i = threadIdx.x; i < 64 * 16; i += 256) w1[i] = W1[i];
    if (threadIdx.x < 16) { sb1[threadIdx.x] = b1[threadIdx.x]; w2[threadIdx.x] = W2[threadIdx.x]; }
    __syncthreads();
    float b2v = b2[0];
    int n = blockIdx.x * blockDim.x + threadIdx.x;
    if (n < N) {
        float hv[64];
        const u32* hp = (const u32*)(h + (u64)n * 64);
#pragma unroll
        for (int i = 0; i < 32; i++) { u32 u = hp[i]; hv[2 * i] = lo16(u); hv[2 * i + 1] = hi16(u); }
        float z = b2v;
        for (int j = 0; j < 16; j++) {
            float acc = sb1[j];
#pragma unroll
            for (int k = 0; k < 64; k++) acc = fmaf(hv[k], w1[k * 16 + j], acc);
            acc = fmaxf(acc, 0.f);
            z = fmaf(acc, w2[j], z);
        }
        out[n] = 1.f / (1.f + __expf(-z));
    }
}

// ---------- launch ----------
extern "C" void kernel_launch(void* const* d_in, const int* in_sizes, int n_in,
                              void* d_out, int out_size, void* d_ws, size_t ws_size,
                              hipStream_t stream) {
    const float* x    = (const float*)d_in[0];
    const int*   ei   = (const int*)d_in[1];
    const float* ea   = (const float*)d_in[2];
    const float* Wl1  = (const float*)d_in[3];
    const float* bl1  = (const float*)d_in[4];
    const float* Wr1  = (const float*)d_in[5];
    const float* br1  = (const float*)d_in[6];
    const float* We1  = (const float*)d_in[7];
    const float* att1 = (const float*)d_in[8];
    const float* bias1= (const float*)d_in[9];
    const float* Wl2  = (const float*)d_in[10];
    const float* bl2  = (const float*)d_in[11];
    const float* Wr2  = (const float*)d_in[12];
    const float* br2  = (const float*)d_in[13];
    const float* We2  = (const float*)d_in[14];
    const float* att2 = (const float*)d_in[15];
    const float* bias2= (const float*)d_in[16];
    const float* W1   = (const float*)d_in[17];
    const float* b1   = (const float*)d_in[18];
    const float* W2   = (const float*)d_in[19];
    const float* b2   = (const float*)d_in[20];
    float* out = (float*)d_out;

    const int N = in_sizes[0] / 128;
    const int E = in_sizes[1] / 2;
    const int* srcv = ei;
    const int* dstv = ei + E;

    uint8_t* p = (uint8_t*)d_ws;
    auto carve = [&](size_t bytes) -> void* {
        void* r = (void*)p;
        p += (bytes + 255) & ~(size_t)255;
        return r;
    };
    int*  deg     = (int*)carve((size_t)N * 4);
    int*  cursor  = (int*)carve((size_t)N * 4);
    int*  offs    = (int*)carve((size_t)(N + 1) * 4);
    int*  partials= (int*)carve(4096);
    int*  csrc    = (int*)carve((size_t)E * 4);
    uint4* cattr  = (uint4*)carve((size_t)E * 32);
    u16*  xl      = (u16*)carve((size_t)N * 64 * 2);
    u16*  xr      = (u16*)carve((size_t)N * 64 * 2);
    u16*  hb      = (u16*)carve((size_t)N * 64 * 2);
    u32*  wb1     = (u32*)carve(8 * 4 * 64 * 16);   // K=128 packed W
    u32*  wb2     = (u32*)carve(8 * 2 * 64 * 16);   // K=64 packed W
    (void)ws_size; (void)n_in; (void)out_size;

    hipMemsetAsync(deg, 0, (size_t)N * 4, stream);

    const int B = 256;
    pack_w<128><<<8, 256, 0, stream>>>(Wl1, Wr1, wb1);
    pack_w<64><<<4, 256, 0, stream>>>(Wl2, Wr2, wb2);

    deg_hist<<<(E + B - 1) / B, B, 0, stream>>>(dstv, E, deg);
    int nb = (N + SCAN_CHUNK - 1) / SCAN_CHUNK;
    scan_partial<<<nb, SCAN_T, 0, stream>>>(deg, N, partials);
    scan_mid<<<1, 64, 0, stream>>>(partials, nb);
    scan_final<<<nb, SCAN_T, 0, stream>>>(deg, N, partials, offs, E);
    hipMemcpyAsync(cursor, offs, (size_t)N * 4, hipMemcpyDeviceToDevice, stream);
    csr_fill_split<<<(E + B - 1) / B, B, 0, stream>>>(srcv, dstv, (const float4*)ea, E,
                                                      cursor, csrc, cattr);

    int gemm_blocks = (N / 16 + 3) / 4;
    // Layer 1
    gemm_mfma<128, true><<<gemm_blocks, 256, 0, stream>>>(x, wb1, bl1, br1, N, xl, xr);
    gat_layer<<<8192, 256, 0, stream>>>(xl, xr, offs, csrc, (const u32*)cattr,
                                        We1, att1, bias1, N, hb);
    // Layer 2
    gemm_mfma<64, false><<<gemm_blocks, 256, 0, stream>>>(hb, wb2, bl2, br2, N, xl, xr);
    gat_layer<<<8192, 256, 0, stream>>>(xl, xr, offs, csrc, (const u32*)cattr,
                                        We2, att2, bias2, N, hb);
    // Head
    mlp_head<<<(N + B - 1) / B, B, 0, stream>>>(hb, W1, b1, W2, b2, N, out);
}